// Round 1
// baseline (3098.887 us; speedup 1.0000x reference)
//
#include <hip/hip_runtime.h>
#include <hip/hip_bf16.h>

#define B_ 2
#define L_ 2048
#define D_ 2048
#define H_ 16
#define E_ 128
#define M_ (B_*L_)     // 4096 rows of x / ao
#define K_ D_          // 2048 reduction dim
#define N3_ (3*D_)     // 6144 qkv cols

// ================= GEMM: C = A @ W^T + bias  (NT, both K-contiguous) ========
// A [M][K] row-major, W [N][K] row-major. BM=BN=128, BK=32, 256 threads,
// 8x8 outputs/thread. mode 0: scatter qkv cols into Q/K/V [B,H,L,E].
// mode 1: plain write to o0 [M][N].
__global__ __launch_bounds__(256)
void gemm_nt(const float* __restrict__ A, const float* __restrict__ W,
             const float* __restrict__ bias,
             float* __restrict__ o0, float* __restrict__ o1, float* __restrict__ o2,
             const int mode)
{
    // transposed tiles: As[k][m], Ws[k][n]; pad 132 so compute-phase reads
    // (lane groups vary ty/tx by 8 floats) spread banks.
    __shared__ float As[32][132];
    __shared__ float Ws[32][132];

    const int t  = threadIdx.x;
    const int tx = t & 15;        // col group (8 cols each)
    const int ty = t >> 4;        // row group (8 rows each)
    const int m0 = blockIdx.y << 7;
    const int n0 = blockIdx.x << 7;

    float acc[8][8];
    #pragma unroll
    for (int i = 0; i < 8; ++i)
        #pragma unroll
        for (int j = 0; j < 8; ++j) acc[i][j] = 0.f;

    const float* Abase = A + (size_t)m0 * K_;
    const float* Wbase = W + (size_t)n0 * K_;

    for (int k0 = 0; k0 < K_; k0 += 32) {
        // stage 128x32 tiles: 1024 float4 per matrix, 4 per thread
        #pragma unroll
        for (int j = 0; j < 4; ++j) {
            const int slot = (j << 8) + t;   // 0..1023
            const int row  = slot >> 3;      // 0..127
            const int kq   = slot & 7;       // float4 index within k-32
            const float4 av = *(const float4*)(Abase + (size_t)row * K_ + k0 + (kq << 2));
            As[(kq << 2) + 0][row] = av.x;
            As[(kq << 2) + 1][row] = av.y;
            As[(kq << 2) + 2][row] = av.z;
            As[(kq << 2) + 3][row] = av.w;
            const float4 wv = *(const float4*)(Wbase + (size_t)row * K_ + k0 + (kq << 2));
            Ws[(kq << 2) + 0][row] = wv.x;
            Ws[(kq << 2) + 1][row] = wv.y;
            Ws[(kq << 2) + 2][row] = wv.z;
            Ws[(kq << 2) + 3][row] = wv.w;
        }
        __syncthreads();
        #pragma unroll
        for (int kk = 0; kk < 32; ++kk) {
            const float4 a0 = *(const float4*)&As[kk][(ty << 3)];
            const float4 a1 = *(const float4*)&As[kk][(ty << 3) + 4];
            const float4 b0 = *(const float4*)&Ws[kk][(tx << 3)];
            const float4 b1 = *(const float4*)&Ws[kk][(tx << 3) + 4];
            const float a[8] = {a0.x,a0.y,a0.z,a0.w,a1.x,a1.y,a1.z,a1.w};
            const float b[8] = {b0.x,b0.y,b0.z,b0.w,b1.x,b1.y,b1.z,b1.w};
            #pragma unroll
            for (int i = 0; i < 8; ++i)
                #pragma unroll
                for (int j = 0; j < 8; ++j)
                    acc[i][j] = fmaf(a[i], b[j], acc[i][j]);
        }
        __syncthreads();
    }

    float bj[8];
    #pragma unroll
    for (int j = 0; j < 8; ++j) bj[j] = bias[n0 + (tx << 3) + j];

    if (mode == 1) {
        #pragma unroll
        for (int i = 0; i < 8; ++i) {
            const int m = m0 + (ty << 3) + i;
            float* dst = o0 + (size_t)m * D_ + n0 + (tx << 3);
            ((float4*)dst)[0] = make_float4(acc[i][0]+bj[0], acc[i][1]+bj[1],
                                            acc[i][2]+bj[2], acc[i][3]+bj[3]);
            ((float4*)dst)[1] = make_float4(acc[i][4]+bj[4], acc[i][5]+bj[5],
                                            acc[i][6]+bj[6], acc[i][7]+bj[7]);
        }
    } else {
        // n0 is 128-aligned -> whole block belongs to one (which, head)
        const int which = n0 >> 11;           // 0=q 1=k 2=v
        const int h     = (n0 & 2047) >> 7;   // head index
        float* dstb = (which == 0) ? o0 : (which == 1) ? o1 : o2;
        #pragma unroll
        for (int i = 0; i < 8; ++i) {
            const int m = m0 + (ty << 3) + i;
            const int b = m >> 11;            // / L_
            const int l = m & 2047;
            float* dst = dstb + ((((size_t)(b * H_ + h)) * L_ + l) << 7) + (tx << 3);
            ((float4*)dst)[0] = make_float4(acc[i][0]+bj[0], acc[i][1]+bj[1],
                                            acc[i][2]+bj[2], acc[i][3]+bj[3]);
            ((float4*)dst)[1] = make_float4(acc[i][4]+bj[4], acc[i][5]+bj[5],
                                            acc[i][6]+bj[6], acc[i][7]+bj[7]);
        }
    }
}

// ================= Flash attention (causal), fp32 ===========================
// grid (L/32, B*H), 256 threads. Q tile 32x128 in LDS, K/V tiles 32x128.
// Each thread owns O row r=t>>3, float4 columns {u+8i} (u=t&7) -> all hot
// LDS b128 reads are conflict-free with 132-float row padding.
__global__ __launch_bounds__(256)
void attn_fwd(const float* __restrict__ Q, const float* __restrict__ Kp,
              const float* __restrict__ Vp, float* __restrict__ O)
{
    __shared__ float Qs[32][132];
    __shared__ float Ks[32][132];
    __shared__ float Vs[32][132];
    __shared__ float Ss[32][36];
    __shared__ float mrow[32], lrow[32], frow[32];

    const int t  = threadIdx.x;
    const int qt = blockIdx.x;
    const int bh = blockIdx.y;
    const float scale = 0.08838834764831843f;  // 1/sqrt(128)

    const float* Qb = Q  + (size_t)bh * (L_ * E_) + ((size_t)(qt << 5)) * E_;
    const float* Kb = Kp + (size_t)bh * (L_ * E_);
    const float* Vb = Vp + (size_t)bh * (L_ * E_);

    #pragma unroll
    for (int j = 0; j < 4; ++j) {
        const int slot = (j << 8) + t;  // 0..1023
        const int row  = slot >> 5;
        const int c4   = slot & 31;
        ((float4*)Qs[row])[c4] = ((const float4*)(Qb + (size_t)row * E_))[c4];
    }
    if (t < 32) { mrow[t] = -1e30f; lrow[t] = 0.f; }

    const int r = t >> 3;
    const int u = t & 7;

    float4 o4[4];
    #pragma unroll
    for (int i = 0; i < 4; ++i) o4[i] = make_float4(0.f, 0.f, 0.f, 0.f);

    __syncthreads();

    for (int kt = 0; kt <= qt; ++kt) {
        #pragma unroll
        for (int j = 0; j < 4; ++j) {
            const int slot = (j << 8) + t;
            const int row  = slot >> 5;
            const int c4   = slot & 31;
            ((float4*)Ks[row])[c4] =
                ((const float4*)(Kb + (size_t)((kt << 5) + row) * E_))[c4];
            ((float4*)Vs[row])[c4] =
                ((const float4*)(Vb + (size_t)((kt << 5) + row) * E_))[c4];
        }
        __syncthreads();

        // S[r][u+8jj] = q_r . k_col
        float sv[4] = {0.f, 0.f, 0.f, 0.f};
        #pragma unroll
        for (int e4 = 0; e4 < 32; ++e4) {
            const float4 qv = ((const float4*)Qs[r])[e4];
            #pragma unroll
            for (int jj = 0; jj < 4; ++jj) {
                const float4 kv = ((const float4*)Ks[u + (jj << 3)])[e4];
                sv[jj] += qv.x*kv.x + qv.y*kv.y + qv.z*kv.z + qv.w*kv.w;
            }
        }
        const int qg = (qt << 5) + r;
        #pragma unroll
        for (int jj = 0; jj < 4; ++jj) {
            const int sc = u + (jj << 3);
            const int kg = (kt << 5) + sc;
            Ss[r][sc] = (kg <= qg) ? sv[jj] * scale : -1e30f;
        }
        __syncthreads();

        // online softmax, one thread per row
        if (t < 32) {
            const float mold = mrow[t];
            float mx = mold;
            #pragma unroll
            for (int c = 0; c < 32; ++c) mx = fmaxf(mx, Ss[t][c]);
            const float f = __expf(mold - mx);
            float sum = 0.f;
            #pragma unroll
            for (int c = 0; c < 32; ++c) {
                const float p = __expf(Ss[t][c] - mx);
                Ss[t][c] = p;
                sum += p;
            }
            mrow[t] = mx;
            frow[t] = f;
            lrow[t] = lrow[t] * f + sum;
        }
        __syncthreads();

        // rescale + PV
        const float f = frow[r];
        #pragma unroll
        for (int i = 0; i < 4; ++i) {
            o4[i].x *= f; o4[i].y *= f; o4[i].z *= f; o4[i].w *= f;
        }
        #pragma unroll
        for (int kk = 0; kk < 32; ++kk) {
            const float p = Ss[r][kk];
            #pragma unroll
            for (int i = 0; i < 4; ++i) {
                const float4 vv = ((const float4*)Vs[kk])[u + (i << 3)];
                o4[i].x = fmaf(p, vv.x, o4[i].x);
                o4[i].y = fmaf(p, vv.y, o4[i].y);
                o4[i].z = fmaf(p, vv.z, o4[i].z);
                o4[i].w = fmaf(p, vv.w, o4[i].w);
            }
        }
        __syncthreads();  // protect Ks/Vs/Ss before next iteration
    }

    const float invl = 1.f / lrow[r];
    const int qg = (qt << 5) + r;
    const int b  = bh >> 4;    // / H_
    const int h  = bh & 15;
    float4* dst = (float4*)(O + (size_t)(b * L_ + qg) * D_ + (h << 7));
    #pragma unroll
    for (int i = 0; i < 4; ++i) {
        float4 w = o4[i];
        w.x *= invl; w.y *= invl; w.z *= invl; w.w *= invl;
        dst[u + (i << 3)] = w;
    }
}

extern "C" void kernel_launch(void* const* d_in, const int* in_sizes, int n_in,
                              void* d_out, int out_size, void* d_ws, size_t ws_size,
                              hipStream_t stream)
{
    const float* x    = (const float*)d_in[0];
    const float* Wqkv = (const float*)d_in[1];
    const float* bqkv = (const float*)d_in[2];
    const float* Wout = (const float*)d_in[3];
    const float* bout = (const float*)d_in[4];
    float* out = (float*)d_out;

    // workspace: Q,K,V [B,H,L,E] + attn-out [B,L,D]  = 128 MiB fp32
    float* q  = (float*)d_ws;
    float* k  = q + (size_t)B_ * H_ * L_ * E_;
    float* v  = k + (size_t)B_ * H_ * L_ * E_;
    float* ao = v + (size_t)B_ * H_ * L_ * E_;

    dim3 blk(256);
    dim3 g1(N3_ / 128, M_ / 128);   // 48 x 32
    gemm_nt<<<g1, blk, 0, stream>>>(x, Wqkv, bqkv, q, k, v, 0);

    dim3 g2(L_ / 32, B_ * H_);      // 64 x 32
    attn_fwd<<<g2, blk, 0, stream>>>(q, k, v, ao);

    dim3 g3(D_ / 128, M_ / 128);    // 16 x 32
    gemm_nt<<<g3, blk, 0, stream>>>(ao, Wout, bout, out, nullptr, nullptr, 1);
}

// Round 3
// 597.721 us; speedup vs baseline: 5.1845x; 5.1845x over previous
//
#include <hip/hip_runtime.h>
#include <hip/hip_bf16.h>

#define B_ 2
#define L_ 2048
#define D_ 2048
#define H_ 16
#define E_ 128
#define M_ 4096
#define K_ 2048
#define N3_ 6144

typedef __attribute__((ext_vector_type(4))) float f32x4;
typedef short s16x8 __attribute__((ext_vector_type(8)));   // 8 bf16 = 4 VGPRs

__device__ inline void gld_lds16(const void* g, void* l) {
    __builtin_amdgcn_global_load_lds(
        (const __attribute__((address_space(1))) void*)g,
        (__attribute__((address_space(3))) void*)l, 16, 0, 0);
}

// ---------------- fp32 -> bf16 cast (vectorized) ----------------------------
__global__ __launch_bounds__(256)
void cast_bf16(const float* __restrict__ in, __hip_bfloat16* __restrict__ out, int n8)
{
    const int i = blockIdx.x * 256 + threadIdx.x;
    if (i >= n8) return;
    const float4 a = ((const float4*)in)[2 * i];
    const float4 b = ((const float4*)in)[2 * i + 1];
    union { __hip_bfloat16 h[8]; uint4 u; } o;
    o.h[0] = __float2bfloat16(a.x); o.h[1] = __float2bfloat16(a.y);
    o.h[2] = __float2bfloat16(a.z); o.h[3] = __float2bfloat16(a.w);
    o.h[4] = __float2bfloat16(b.x); o.h[5] = __float2bfloat16(b.y);
    o.h[6] = __float2bfloat16(b.z); o.h[7] = __float2bfloat16(b.w);
    ((uint4*)out)[i] = o.u;
}

// ---------------- bf16 MFMA GEMM (m97 structure): C = A @ W^T + bias --------
// A [M][K] bf16 row-major, W [N][K] bf16 row-major. 128x128 tile, BK=32,
// 4 waves, each wave 64x64 (4x4 frags of 16x16x32). Linear LDS [128][32],
// staged with global_load_lds width=16.
// mode 0: scatter into q/k/v bf16 [B,H,L,E]. mode 1: o fp32 [M][N].
__global__ __launch_bounds__(256)
void gemm_bf16_nt(const __hip_bfloat16* __restrict__ A,
                  const __hip_bfloat16* __restrict__ W,
                  const float* __restrict__ bias,
                  __hip_bfloat16* __restrict__ q,
                  __hip_bfloat16* __restrict__ k,
                  __hip_bfloat16* __restrict__ v,
                  float* __restrict__ o,
                  const int mode)
{
    __shared__ __hip_bfloat16 As[128 * 32];   // 8 KB
    __shared__ __hip_bfloat16 Bs[128 * 32];   // 8 KB

    const int t    = threadIdx.x;
    const int lane = t & 63;
    const int w    = t >> 6;
    const int l15  = lane & 15;
    const int hi   = lane >> 4;
    const int wr   = w >> 1, wc = w & 1;
    const int m0   = blockIdx.y << 7;
    const int n0   = blockIdx.x << 7;

    f32x4 acc[4][4];
    const f32x4 z4 = {0.f, 0.f, 0.f, 0.f};
    #pragma unroll
    for (int m = 0; m < 4; ++m)
        #pragma unroll
        for (int n = 0; n < 4; ++n) acc[m][n] = z4;

    const __hip_bfloat16* Ab = A + (size_t)m0 * K_;
    const __hip_bfloat16* Bb = W + (size_t)n0 * K_;
    const int srow = t >> 2;          // 0..63
    const int sc   = (t & 3) << 3;    // k-chunk of 8 bf16

    for (int k0 = 0; k0 < K_; k0 += 32) {
        #pragma unroll
        for (int j = 0; j < 2; ++j) {
            gld_lds16(Ab + (size_t)(j * 64 + srow) * K_ + k0 + sc,
                      (char*)As + j * 4096 + w * 1024);
            gld_lds16(Bb + (size_t)(j * 64 + srow) * K_ + k0 + sc,
                      (char*)Bs + j * 4096 + w * 1024);
        }
        __syncthreads();
        s16x8 af[4], bf[4];
        #pragma unroll
        for (int m = 0; m < 4; ++m)
            af[m] = *(const s16x8*)(As + (wr * 64 + m * 16 + l15) * 32 + hi * 8);
        #pragma unroll
        for (int n = 0; n < 4; ++n)
            bf[n] = *(const s16x8*)(Bs + (wc * 64 + n * 16 + l15) * 32 + hi * 8);
        #pragma unroll
        for (int m = 0; m < 4; ++m)
            #pragma unroll
            for (int n = 0; n < 4; ++n)
                acc[m][n] = __builtin_amdgcn_mfma_f32_16x16x32_bf16(af[m], bf[n], acc[m][n], 0, 0, 0);
        __syncthreads();
    }

    if (mode == 1) {
        #pragma unroll
        for (int n = 0; n < 4; ++n) {
            const int col = n0 + wc * 64 + n * 16 + l15;
            const float bn = bias[col];
            #pragma unroll
            for (int m = 0; m < 4; ++m) {
                const int rowb = m0 + wr * 64 + m * 16 + hi * 4;
                #pragma unroll
                for (int i = 0; i < 4; ++i)
                    o[(size_t)(rowb + i) * D_ + col] = acc[m][n][i] + bn;
            }
        }
    } else {
        const int which = n0 >> 11;           // 0=q 1=k 2=v
        const int h     = (n0 >> 7) & 15;
        __hip_bfloat16* dstb = (which == 0) ? q : (which == 1) ? k : v;
        #pragma unroll
        for (int n = 0; n < 4; ++n) {
            const int e  = wc * 64 + n * 16 + l15;         // 0..127 in head
            const float bn = bias[n0 + e];
            #pragma unroll
            for (int m = 0; m < 4; ++m) {
                const int rowb = m0 + wr * 64 + m * 16 + hi * 4;
                #pragma unroll
                for (int i = 0; i < 4; ++i) {
                    const int mm = rowb + i;
                    const int b  = mm >> 11;
                    const int l  = mm & 2047;
                    dstb[((size_t)((b * H_ + h) * L_ + l) << 7) + e] =
                        __float2bfloat16(acc[m][n][i] + bn);
                }
            }
        }
    }
}

// ---------------- bf16 MFMA causal flash attention --------------------------
// grid (L/64, B*H), 256 thr (4 waves). Wave w owns 16 q-rows. KV tiles of 64.
// K LDS [64][128] chunk-XOR-swizzled via pre-swizzled global_load_lds source;
// V LDS transposed [e=128][kv=64] chunk-XOR-swizzled, reg-staged;
// P per-wave LDS [16][64] chunk-XOR-swizzled.
__global__ __launch_bounds__(256)
void attn_mfma(const __hip_bfloat16* __restrict__ Qg,
               const __hip_bfloat16* __restrict__ Kg,
               const __hip_bfloat16* __restrict__ Vg,
               __hip_bfloat16* __restrict__ O)
{
    __shared__ __hip_bfloat16 Ks[64 * 128];    // 16 KB
    __shared__ __hip_bfloat16 Vt[128 * 64];    // 16 KB
    __shared__ __hip_bfloat16 Ps[4 * 1024];    // 8 KB (2 KB per wave)

    const int t    = threadIdx.x;
    const int lane = t & 63;
    const int w    = t >> 6;
    const int l15  = lane & 15;
    const int hi   = lane >> 4;
    const int qt   = gridDim.x - 1 - blockIdx.x;   // longest blocks first
    const int bh   = blockIdx.y;
    const size_t base = (size_t)bh * (L_ * E_);
    const int q0   = (qt << 6) + (w << 4);
    const float scale = 0.08838834764831843f;      // 1/sqrt(128)

    // Q fragments: row=l15 (q), k = e0*32 + hi*8 + r
    s16x8 qf[4];
    #pragma unroll
    for (int e0 = 0; e0 < 4; ++e0)
        qf[e0] = *(const s16x8*)(Qg + base + (size_t)(q0 + l15) * E_ + e0 * 32 + hi * 8);

    f32x4 oacc[8];
    const f32x4 z4 = {0.f, 0.f, 0.f, 0.f};
    #pragma unroll
    for (int ef = 0; ef < 8; ++ef) oacc[ef] = z4;
    float mrow[4] = {-1e30f, -1e30f, -1e30f, -1e30f};
    float lrow[4] = {0.f, 0.f, 0.f, 0.f};

    const int krow = t >> 4;    // 0..15
    const int kc16 = t & 15;    // 16B chunk within row

    for (int kt = 0; kt <= qt; ++kt) {
        const __hip_bfloat16* Kb = Kg + base + ((size_t)(kt << 6)) * E_;
        const __hip_bfloat16* Vb = Vg + base + ((size_t)(kt << 6)) * E_;
        // ---- stage K (swizzled source -> linear LDS) ----
        #pragma unroll
        for (int j = 0; j < 4; ++j) {
            const int row = (j << 4) + krow;
            const int csw = kc16 ^ (row & 7);
            gld_lds16(Kb + (size_t)row * E_ + (csw << 3),
                      (char*)Ks + (j << 12) + (w << 10));
        }
        // ---- stage V transposed (reg, rotated scalar writes) ----
        #pragma unroll
        for (int j = 0; j < 4; ++j) {
            const int kv = (j << 4) + krow;
            union { uint4 u; __hip_bfloat16 h[8]; } vv;
            vv.u = *(const uint4*)(Vb + (size_t)kv * E_ + (kc16 << 3));
            #pragma unroll
            for (int x = 0; x < 8; ++x) {
                const int xr = (x + kc16) & 7;          // write-order rotation
                const int e  = (kc16 << 3) + xr;
                const int by = (e << 7) + ((((kv >> 3) ^ (e & 7)) << 4) | ((kv & 7) << 1));
                *(__hip_bfloat16*)((char*)Vt + by) = vv.h[xr];
            }
        }
        __syncthreads();

        // ---- S = Q K^T : 4 kv-frags x 4 e-steps ----
        f32x4 sf[4];
        #pragma unroll
        for (int c = 0; c < 4; ++c) {
            f32x4 s = z4;
            const int row = (c << 4) + l15;              // kv row in tile
            #pragma unroll
            for (int e0 = 0; e0 < 4; ++e0) {
                const int ch = ((e0 << 2) + hi) ^ (row & 7);
                const s16x8 kf = *(const s16x8*)((char*)Ks + (row << 8) + (ch << 4));
                s = __builtin_amdgcn_mfma_f32_16x16x32_bf16(qf[e0], kf, s, 0, 0, 0);
            }
            sf[c] = s;
        }

        // ---- scale, causal mask, online softmax (wave-parallel) ----
        const int qg = q0 + (hi << 2);
        float p[4][4];
        float tmax[4] = {-1e30f, -1e30f, -1e30f, -1e30f};
        #pragma unroll
        for (int c = 0; c < 4; ++c) {
            const int kvg = (kt << 6) + (c << 4) + l15;
            #pragma unroll
            for (int i = 0; i < 4; ++i) {
                float s = sf[c][i] * scale;
                if (kvg > qg + i) s = -1e30f;
                p[c][i] = s;
                tmax[i] = fmaxf(tmax[i], s);
            }
        }
        float fsc[4];
        #pragma unroll
        for (int i = 0; i < 4; ++i) {
            float v = tmax[i];
            v = fmaxf(v, __shfl_xor(v, 1));
            v = fmaxf(v, __shfl_xor(v, 2));
            v = fmaxf(v, __shfl_xor(v, 4));
            v = fmaxf(v, __shfl_xor(v, 8));
            const float mnew = fmaxf(mrow[i], v);
            fsc[i] = __expf(mrow[i] - mnew);
            mrow[i] = mnew;
            float sum = 0.f;
            #pragma unroll
            for (int c = 0; c < 4; ++c) {
                const float pe = __expf(p[c][i] - mnew);
                p[c][i] = pe;
                sum += pe;
            }
            sum += __shfl_xor(sum, 1);
            sum += __shfl_xor(sum, 2);
            sum += __shfl_xor(sum, 4);
            sum += __shfl_xor(sum, 8);
            lrow[i] = lrow[i] * fsc[i] + sum;
        }
        #pragma unroll
        for (int ef = 0; ef < 8; ++ef)
            #pragma unroll
            for (int i = 0; i < 4; ++i) oacc[ef][i] *= fsc[i];

        // ---- P -> LDS (bf16, swizzled), then PV ----
        #pragma unroll
        for (int c = 0; c < 4; ++c)
            #pragma unroll
            for (int i = 0; i < 4; ++i) {
                const int r   = (hi << 2) + i;
                const int col = (c << 4) + l15;
                const int ch  = (col >> 3) ^ (r & 7);
                const int by  = (r << 7) + ((ch << 4) | ((col & 7) << 1));
                *(__hip_bfloat16*)((char*)Ps + (w << 11) + by) = __float2bfloat16(p[c][i]);
            }
        asm volatile("s_waitcnt lgkmcnt(0)" ::: "memory");

        #pragma unroll
        for (int kh = 0; kh < 2; ++kh) {
            const int chp = ((kh << 2) + hi) ^ (l15 & 7);
            const s16x8 pa = *(const s16x8*)((char*)Ps + (w << 11) + (l15 << 7) + (chp << 4));
            #pragma unroll
            for (int ef = 0; ef < 8; ++ef) {
                const int e   = (ef << 4) + l15;
                const int chv = ((kh << 2) + hi) ^ (e & 7);
                const s16x8 vb = *(const s16x8*)((char*)Vt + (e << 7) + (chv << 4));
                oacc[ef] = __builtin_amdgcn_mfma_f32_16x16x32_bf16(pa, vb, oacc[ef], 0, 0, 0);
            }
        }
        __syncthreads();
    }

    // ---- epilogue: O -> ao bf16 [B][L][D] ----
    const int b = bh >> 4, h = bh & 15;
    float invl[4];
    #pragma unroll
    for (int i = 0; i < 4; ++i) invl[i] = 1.f / lrow[i];
    #pragma unroll
    for (int ef = 0; ef < 8; ++ef) {
        const int e = (ef << 4) + l15;
        #pragma unroll
        for (int i = 0; i < 4; ++i) {
            const int row = q0 + (hi << 2) + i;
            O[((size_t)(b * L_ + row) * D_) + (h << 7) + e] =
                __float2bfloat16(oacc[ef][i] * invl[i]);
        }
    }
}

extern "C" void kernel_launch(void* const* d_in, const int* in_sizes, int n_in,
                              void* d_out, int out_size, void* d_ws, size_t ws_size,
                              hipStream_t stream)
{
    const float* x    = (const float*)d_in[0];
    const float* Wqkv = (const float*)d_in[1];
    const float* bqkv = (const float*)d_in[2];
    const float* Wout = (const float*)d_in[3];
    const float* bout = (const float*)d_in[4];
    float* out = (float*)d_out;

    __hip_bfloat16* xb  = (__hip_bfloat16*)d_ws;
    __hip_bfloat16* wqb = xb  + (size_t)M_ * K_;          //  8,388,608
    __hip_bfloat16* wob = wqb + (size_t)N3_ * K_;         // 12,582,912
    __hip_bfloat16* qb  = wob + (size_t)D_ * K_;          //  4,194,304
    __hip_bfloat16* kb  = qb  + (size_t)M_ * D_;
    __hip_bfloat16* vb  = kb  + (size_t)M_ * D_;
    __hip_bfloat16* aob = vb  + (size_t)M_ * D_;

    cast_bf16<<<(M_ * K_ / 8) / 256, 256, 0, stream>>>(x, xb, M_ * K_ / 8);
    cast_bf16<<<(N3_ * K_ / 8) / 256, 256, 0, stream>>>(Wqkv, wqb, N3_ * K_ / 8);
    cast_bf16<<<(D_ * K_ / 8) / 256, 256, 0, stream>>>(Wout, wob, D_ * K_ / 8);

    dim3 blk(256);
    dim3 g1(N3_ / 128, M_ / 128);   // 48 x 32
    gemm_bf16_nt<<<g1, blk, 0, stream>>>(xb, wqb, bqkv, qb, kb, vb, nullptr, 0);

    dim3 g2(L_ / 64, B_ * H_);      // 32 x 32
    attn_mfma<<<g2, blk, 0, stream>>>(qb, kb, vb, aob);

    dim3 g3(D_ / 128, M_ / 128);    // 16 x 32
    gemm_bf16_nt<<<g3, blk, 0, stream>>>(aob, wob, bout, nullptr, nullptr, nullptr, out, 1);
}

// Round 5
// 446.971 us; speedup vs baseline: 6.9331x; 1.3373x over previous
//
#include <hip/hip_runtime.h>
#include <hip/hip_bf16.h>

#define B_ 2
#define L_ 2048
#define D_ 2048
#define H_ 16
#define E_ 128
#define M_ 4096
#define K_ 2048
#define N3_ 6144

typedef __attribute__((ext_vector_type(4))) float f32x4;
typedef short s16x8 __attribute__((ext_vector_type(8)));   // 8 bf16 = 4 VGPRs

__device__ inline void gld_lds16(const void* g, void* l) {
    __builtin_amdgcn_global_load_lds(
        (const __attribute__((address_space(1))) void*)g,
        (__attribute__((address_space(3))) void*)l, 16, 0, 0);
}

// ---------------- fp32 -> bf16 cast (vectorized) ----------------------------
__global__ __launch_bounds__(256)
void cast_bf16(const float* __restrict__ in, __hip_bfloat16* __restrict__ out, int n8)
{
    const int i = blockIdx.x * 256 + threadIdx.x;
    if (i >= n8) return;
    const float4 a = ((const float4*)in)[2 * i];
    const float4 b = ((const float4*)in)[2 * i + 1];
    union { __hip_bfloat16 h[8]; uint4 u; } o;
    o.h[0] = __float2bfloat16(a.x); o.h[1] = __float2bfloat16(a.y);
    o.h[2] = __float2bfloat16(a.z); o.h[3] = __float2bfloat16(a.w);
    o.h[4] = __float2bfloat16(b.x); o.h[5] = __float2bfloat16(b.y);
    o.h[6] = __float2bfloat16(b.z); o.h[7] = __float2bfloat16(b.w);
    ((uint4*)out)[i] = o.u;
}

// ---------------- bf16 MFMA GEMM (m97 structure): C = A @ W^T + bias --------
// mode 0: scatter into q[b,h,l,e], k[b,h,l,e], vT[b,h,e,l] bf16.
// mode 1: o fp32 [M][N].
__global__ __launch_bounds__(256)
void gemm_bf16_nt(const __hip_bfloat16* __restrict__ A,
                  const __hip_bfloat16* __restrict__ W,
                  const float* __restrict__ bias,
                  __hip_bfloat16* __restrict__ q,
                  __hip_bfloat16* __restrict__ k,
                  __hip_bfloat16* __restrict__ vT,
                  float* __restrict__ o,
                  const int mode)
{
    __shared__ __hip_bfloat16 As[128 * 32];   // 8 KB
    __shared__ __hip_bfloat16 Bs[128 * 32];   // 8 KB

    const int t    = threadIdx.x;
    const int lane = t & 63;
    const int w    = t >> 6;
    const int l15  = lane & 15;
    const int hi   = lane >> 4;
    const int wr   = w >> 1, wc = w & 1;
    const int m0   = blockIdx.y << 7;
    const int n0   = blockIdx.x << 7;

    f32x4 acc[4][4];
    const f32x4 z4 = {0.f, 0.f, 0.f, 0.f};
    #pragma unroll
    for (int m = 0; m < 4; ++m)
        #pragma unroll
        for (int n = 0; n < 4; ++n) acc[m][n] = z4;

    const __hip_bfloat16* Ab = A + (size_t)m0 * K_;
    const __hip_bfloat16* Bb = W + (size_t)n0 * K_;
    const int srow = t >> 2;          // 0..63
    const int sc   = (t & 3) << 3;    // k-chunk of 8 bf16

    for (int k0 = 0; k0 < K_; k0 += 32) {
        #pragma unroll
        for (int j = 0; j < 2; ++j) {
            gld_lds16(Ab + (size_t)(j * 64 + srow) * K_ + k0 + sc,
                      (char*)As + j * 4096 + w * 1024);
            gld_lds16(Bb + (size_t)(j * 64 + srow) * K_ + k0 + sc,
                      (char*)Bs + j * 4096 + w * 1024);
        }
        __syncthreads();
        s16x8 af[4], bf[4];
        #pragma unroll
        for (int m = 0; m < 4; ++m)
            af[m] = *(const s16x8*)(As + (wr * 64 + m * 16 + l15) * 32 + hi * 8);
        #pragma unroll
        for (int n = 0; n < 4; ++n)
            bf[n] = *(const s16x8*)(Bs + (wc * 64 + n * 16 + l15) * 32 + hi * 8);
        #pragma unroll
        for (int m = 0; m < 4; ++m)
            #pragma unroll
            for (int n = 0; n < 4; ++n)
                acc[m][n] = __builtin_amdgcn_mfma_f32_16x16x32_bf16(af[m], bf[n], acc[m][n], 0, 0, 0);
        __syncthreads();
    }

    if (mode == 1) {
        #pragma unroll
        for (int n = 0; n < 4; ++n) {
            const int col = n0 + wc * 64 + n * 16 + l15;
            const float bn = bias[col];
            #pragma unroll
            for (int m = 0; m < 4; ++m) {
                const int rowb = m0 + wr * 64 + m * 16 + hi * 4;
                #pragma unroll
                for (int i = 0; i < 4; ++i)
                    o[(size_t)(rowb + i) * D_ + col] = acc[m][n][i] + bn;
            }
        }
    } else {
        const int which = n0 >> 11;           // 0=q 1=k 2=v
        const int h     = (n0 >> 7) & 15;
        #pragma unroll
        for (int n = 0; n < 4; ++n) {
            const int e  = wc * 64 + n * 16 + l15;         // 0..127 in head
            const float bn = bias[n0 + e];
            #pragma unroll
            for (int m = 0; m < 4; ++m) {
                const int rowb = m0 + wr * 64 + m * 16 + hi * 4;
                #pragma unroll
                for (int i = 0; i < 4; ++i) {
                    const int mm = rowb + i;
                    const int b  = mm >> 11;
                    const int l  = mm & 2047;
                    const __hip_bfloat16 val = __float2bfloat16(acc[m][n][i] + bn);
                    if (which == 0)
                        q[((size_t)((b * H_ + h) * L_ + l) << 7) + e] = val;
                    else if (which == 1)
                        k[((size_t)((b * H_ + h) * L_ + l) << 7) + e] = val;
                    else  // V transposed: vT[b][h][e][l]
                        vT[(((size_t)(b * H_ + h) << 7) + e) * L_ + l] = val;
                }
            }
        }
    }
}

// ---------------- bf16 MFMA causal flash attention v2 -----------------------
// grid (16, B*H), 256 thr (4 waves). Block p handles q-tiles {31-p, p}
// (balanced: 33 kv-tile iters each). KV tiles of 64, double-buffered LDS,
// prefetch issued before compute (2-phase). V comes pre-transposed from
// global vT[b,h,e,l], staged via global_load_lds with pre-swizzled source.
__global__ __launch_bounds__(256)
void attn_mfma(const __hip_bfloat16* __restrict__ Qg,
               const __hip_bfloat16* __restrict__ Kg,
               const __hip_bfloat16* __restrict__ vTg,
               __hip_bfloat16* __restrict__ O)
{
    __shared__ __hip_bfloat16 Ks[2][64 * 128];   // 2 x 16 KB
    __shared__ __hip_bfloat16 Vt[2][128 * 64];   // 2 x 16 KB
    __shared__ __hip_bfloat16 Ps[4 * 1024];      // 8 KB (2 KB per wave)

    const int t    = threadIdx.x;
    const int lane = t & 63;
    const int w    = t >> 6;
    const int l15  = lane & 15;
    const int hi   = lane >> 4;
    const int pq   = blockIdx.x;                 // 0..15
    const int bh   = blockIdx.y;
    const size_t base = (size_t)bh * (L_ * E_);  // same for Q/K and vT
    const float scale = 0.08838834764831843f;    // 1/sqrt(128)
    const int krow = t >> 4;                     // 0..15
    const int kc16 = t & 15;

    const __hip_bfloat16* Kbh  = Kg  + base;
    const __hip_bfloat16* vTbh = vTg + base;

    // stage one K/V tile (64 kv rows) into buffer `buf`
    auto stage = [&](int kt2, int buf) {
        const __hip_bfloat16* Kb = Kbh + ((size_t)(kt2 << 6)) * E_;
        char* kd = (char*)Ks + buf * 16384 + (w << 10);
        #pragma unroll
        for (int j = 0; j < 4; ++j) {
            const int row = (j << 4) + krow;
            const int csw = kc16 ^ (row & 7);
            gld_lds16(Kb + (size_t)row * E_ + (csw << 3), kd + (j << 12));
        }
        const __hip_bfloat16* Vb = vTbh + (kt2 << 6);   // column offset kv0
        char* vd = (char*)Vt + buf * 16384 + (w << 10);
        #pragma unroll
        for (int j = 0; j < 4; ++j) {
            const int e  = (j << 5) + (t >> 3);         // 0..127
            const int g8 = (t & 7) ^ (e & 7);
            gld_lds16(Vb + (size_t)e * L_ + (g8 << 3), vd + (j << 12));
        }
    };

    const f32x4 z4 = {0.f, 0.f, 0.f, 0.f};

    #pragma unroll 1
    for (int seg = 0; seg < 2; ++seg) {
        const int qt = seg ? pq : 31 - pq;
        const int q0 = (qt << 6) + (w << 4);

        // Q fragments: row=l15 (q), k = e0*32 + hi*8 + r
        s16x8 qf[4];
        #pragma unroll
        for (int e0 = 0; e0 < 4; ++e0)
            qf[e0] = *(const s16x8*)(Qg + base + (size_t)(q0 + l15) * E_ + e0 * 32 + hi * 8);

        f32x4 oacc[8];
        #pragma unroll
        for (int ef = 0; ef < 8; ++ef) oacc[ef] = z4;
        float mrow[4] = {-1e30f, -1e30f, -1e30f, -1e30f};
        float lrow[4] = {0.f, 0.f, 0.f, 0.f};

        stage(0, 0);
        __syncthreads();

        for (int kt = 0; kt <= qt; ++kt) {
            const int cur = kt & 1;
            if (kt < qt) stage(kt + 1, cur ^ 1);   // prefetch overlaps compute

            const char* Ksc = (const char*)Ks + cur * 16384;
            const char* Vtc = (const char*)Vt + cur * 16384;

            // ---- S = Q K^T : 4 kv-frags x 4 e-steps ----
            f32x4 sf[4];
            #pragma unroll
            for (int c = 0; c < 4; ++c) {
                f32x4 s = z4;
                const int row = (c << 4) + l15;          // kv row in tile
                #pragma unroll
                for (int e0 = 0; e0 < 4; ++e0) {
                    const int ch = ((e0 << 2) + hi) ^ (row & 7);
                    const s16x8 kf = *(const s16x8*)(Ksc + (row << 8) + (ch << 4));
                    s = __builtin_amdgcn_mfma_f32_16x16x32_bf16(qf[e0], kf, s, 0, 0, 0);
                }
                sf[c] = s;
            }

            // ---- scale, causal mask (diag tile only), online softmax ----
            float p4[4][4];
            float tmax[4] = {-1e30f, -1e30f, -1e30f, -1e30f};
            if (kt == qt) {
                const int qg = q0 + (hi << 2);
                #pragma unroll
                for (int c = 0; c < 4; ++c) {
                    const int kvg = (kt << 6) + (c << 4) + l15;
                    #pragma unroll
                    for (int i = 0; i < 4; ++i) {
                        float s = sf[c][i] * scale;
                        if (kvg > qg + i) s = -1e30f;
                        p4[c][i] = s;
                        tmax[i] = fmaxf(tmax[i], s);
                    }
                }
            } else {
                #pragma unroll
                for (int c = 0; c < 4; ++c)
                    #pragma unroll
                    for (int i = 0; i < 4; ++i) {
                        const float s = sf[c][i] * scale;
                        p4[c][i] = s;
                        tmax[i] = fmaxf(tmax[i], s);
                    }
            }
            float fsc[4];
            #pragma unroll
            for (int i = 0; i < 4; ++i) {
                float v = tmax[i];
                v = fmaxf(v, __shfl_xor(v, 1));
                v = fmaxf(v, __shfl_xor(v, 2));
                v = fmaxf(v, __shfl_xor(v, 4));
                v = fmaxf(v, __shfl_xor(v, 8));
                const float mnew = fmaxf(mrow[i], v);
                fsc[i] = __expf(mrow[i] - mnew);
                mrow[i] = mnew;
                float sum = 0.f;
                #pragma unroll
                for (int c = 0; c < 4; ++c) {
                    const float pe = __expf(p4[c][i] - mnew);
                    p4[c][i] = pe;
                    sum += pe;
                }
                sum += __shfl_xor(sum, 1);
                sum += __shfl_xor(sum, 2);
                sum += __shfl_xor(sum, 4);
                sum += __shfl_xor(sum, 8);
                lrow[i] = lrow[i] * fsc[i] + sum;
            }
            #pragma unroll
            for (int ef = 0; ef < 8; ++ef)
                #pragma unroll
                for (int i = 0; i < 4; ++i) oacc[ef][i] *= fsc[i];

            // ---- P -> LDS (bf16, swizzled), then PV ----
            #pragma unroll
            for (int c = 0; c < 4; ++c)
                #pragma unroll
                for (int i = 0; i < 4; ++i) {
                    const int r   = (hi << 2) + i;
                    const int col = (c << 4) + l15;
                    const int ch  = (col >> 3) ^ (r & 7);
                    const int by  = (r << 7) + ((ch << 4) | ((col & 7) << 1));
                    *(__hip_bfloat16*)((char*)Ps + (w << 11) + by) = __float2bfloat16(p4[c][i]);
                }
            asm volatile("s_waitcnt lgkmcnt(0)" ::: "memory");

            #pragma unroll
            for (int kh = 0; kh < 2; ++kh) {
                const int chp = ((kh << 2) + hi) ^ (l15 & 7);
                const s16x8 pa = *(const s16x8*)((char*)Ps + (w << 11) + (l15 << 7) + (chp << 4));
                #pragma unroll
                for (int ef = 0; ef < 8; ++ef) {
                    const int e   = (ef << 4) + l15;
                    const int chv = ((kh << 2) + hi) ^ (e & 7);
                    const s16x8 vb = *(const s16x8*)(Vtc + (e << 7) + (chv << 4));
                    oacc[ef] = __builtin_amdgcn_mfma_f32_16x16x32_bf16(pa, vb, oacc[ef], 0, 0, 0);
                }
            }
            __syncthreads();   // drains prefetch (vmcnt) + protects buffers
        }

        // ---- epilogue: O -> ao bf16 [B][L][D] ----
        const int b = bh >> 4, h = bh & 15;
        float invl[4];
        #pragma unroll
        for (int i = 0; i < 4; ++i) invl[i] = 1.f / lrow[i];
        #pragma unroll
        for (int ef = 0; ef < 8; ++ef) {
            const int e = (ef << 4) + l15;
            #pragma unroll
            for (int i = 0; i < 4; ++i) {
                const int row = q0 + (hi << 2) + i;
                O[((size_t)(b * L_ + row) * D_) + (h << 7) + e] =
                    __float2bfloat16(oacc[ef][i] * invl[i]);
            }
        }
    }
}

extern "C" void kernel_launch(void* const* d_in, const int* in_sizes, int n_in,
                              void* d_out, int out_size, void* d_ws, size_t ws_size,
                              hipStream_t stream)
{
    const float* x    = (const float*)d_in[0];
    const float* Wqkv = (const float*)d_in[1];
    const float* bqkv = (const float*)d_in[2];
    const float* Wout = (const float*)d_in[3];
    const float* bout = (const float*)d_in[4];
    float* out = (float*)d_out;

    __hip_bfloat16* xb  = (__hip_bfloat16*)d_ws;
    __hip_bfloat16* wqb = xb  + (size_t)M_ * K_;
    __hip_bfloat16* wob = wqb + (size_t)N3_ * K_;
    __hip_bfloat16* qb  = wob + (size_t)D_ * K_;
    __hip_bfloat16* kb  = qb  + (size_t)M_ * D_;
    __hip_bfloat16* vtb = kb  + (size_t)M_ * D_;   // vT[b,h,e,l]
    __hip_bfloat16* aob = vtb + (size_t)M_ * D_;

    cast_bf16<<<(M_ * K_ / 8) / 256, 256, 0, stream>>>(x, xb, M_ * K_ / 8);
    cast_bf16<<<(N3_ * K_ / 8) / 256, 256, 0, stream>>>(Wqkv, wqb, N3_ * K_ / 8);
    cast_bf16<<<(D_ * K_ / 8) / 256, 256, 0, stream>>>(Wout, wob, D_ * K_ / 8);

    dim3 blk(256);
    dim3 g1(N3_ / 128, M_ / 128);   // 48 x 32
    gemm_bf16_nt<<<g1, blk, 0, stream>>>(xb, wqb, bqkv, qb, kb, vtb, nullptr, 0);

    dim3 g2(16, B_ * H_);           // paired q-tiles: 16 x 32 = 512 blocks
    attn_mfma<<<g2, blk, 0, stream>>>(qb, kb, vtb, aob);

    dim3 g3(D_ / 128, M_ / 128);    // 16 x 32
    gemm_bf16_nt<<<g3, blk, 0, stream>>>(aob, wob, bout, nullptr, nullptr, nullptr, out, 1);
}

// Round 6
// 427.393 us; speedup vs baseline: 7.2507x; 1.0458x over previous
//
#include <hip/hip_runtime.h>
#include <hip/hip_bf16.h>

#define B_ 2
#define L_ 2048
#define D_ 2048
#define H_ 16
#define E_ 128
#define M_ 4096
#define K_ 2048
#define N3_ 6144

typedef __attribute__((ext_vector_type(4))) float f32x4;
typedef short s16x8 __attribute__((ext_vector_type(8)));   // 8 bf16 = 4 VGPRs

__device__ inline void gld_lds16(const void* g, void* l) {
    __builtin_amdgcn_global_load_lds(
        (const __attribute__((address_space(1))) void*)g,
        (__attribute__((address_space(3))) void*)l, 16, 0, 0);
}

// ---------------- fp32 -> bf16 cast (vectorized) ----------------------------
__global__ __launch_bounds__(256)
void cast_bf16(const float* __restrict__ in, __hip_bfloat16* __restrict__ out, int n8)
{
    const int i = blockIdx.x * 256 + threadIdx.x;
    if (i >= n8) return;
    const float4 a = ((const float4*)in)[2 * i];
    const float4 b = ((const float4*)in)[2 * i + 1];
    union { __hip_bfloat16 h[8]; uint4 u; } o;
    o.h[0] = __float2bfloat16(a.x); o.h[1] = __float2bfloat16(a.y);
    o.h[2] = __float2bfloat16(a.z); o.h[3] = __float2bfloat16(a.w);
    o.h[4] = __float2bfloat16(b.x); o.h[5] = __float2bfloat16(b.y);
    o.h[6] = __float2bfloat16(b.z); o.h[7] = __float2bfloat16(b.w);
    ((uint4*)out)[i] = o.u;
}

// ======== 256x256 8-phase bf16 GEMM (QKV): qkv = x @ Wqkv^T + b =============
// 512 thr (8 waves, 2x4), BK=64, dbuf LDS 128 KiB, XOR-swizzled chunks,
// 4 phases per K-tile: {ds-read subtile | stage 1 half-tile | barrier |
// setprio+16 MFMA | barrier}; full drain only at tile boundary.
// Epilogue scatters q[b,h,l,e], k[b,h,l,e], vT[b,h,e,l].
__global__ __launch_bounds__(512, 2)
void gemm_qkv_8ph(const __hip_bfloat16* __restrict__ A,
                  const __hip_bfloat16* __restrict__ W,
                  const float* __restrict__ bias,
                  __hip_bfloat16* __restrict__ q,
                  __hip_bfloat16* __restrict__ k,
                  __hip_bfloat16* __restrict__ vT)
{
    __shared__ char lds[131072];   // [buf][A 32KB | B 32KB]

    const int t    = threadIdx.x;
    const int lane = t & 63;
    const int w    = t >> 6;      // 0..7
    const int l15  = lane & 15;
    const int hi   = lane >> 4;
    const int wr   = w >> 2;      // 0..1  (row half: 128 rows)
    const int wc   = w & 3;       // 0..3  (col quarter: 64 cols)
    const int n0   = blockIdx.x << 8;
    const int m0   = blockIdx.y << 8;

    f32x4 acc[8][4];
    const f32x4 z4 = {0.f, 0.f, 0.f, 0.f};
    #pragma unroll
    for (int m = 0; m < 8; ++m)
        #pragma unroll
        for (int n = 0; n < 4; ++n) acc[m][n] = z4;
    s16x8 afr[4][2], bfr[4][2];

    const __hip_bfloat16* Abase = A + (size_t)m0 * K_;
    const __hip_bfloat16* Wbase = W + (size_t)n0 * K_;

    // stage one 128x64 half-tile: linear LDS dest, inverse-swizzled source
    auto stage_half = [&](const __hip_bfloat16* src, char* dst) {
        #pragma unroll
        for (int i = 0; i < 2; ++i) {
            const int slot = (i << 9) + t;          // 0..1023
            const int row  = slot >> 3;             // 0..127
            const int csw  = (slot & 7) ^ (row & 7);
            gld_lds16(src + (size_t)row * K_ + (csw << 3),
                      dst + (i << 13) + (w << 10));
        }
    };

    // prologue: tile 0 -> buf 0
    stage_half(Abase,                     lds);
    stage_half(Abase + (size_t)128 * K_,  lds + 16384);
    stage_half(Wbase,                     lds + 32768);
    stage_half(Wbase + (size_t)128 * K_,  lds + 49152);
    __syncthreads();

    const int NT = K_ / 64;   // 32
    for (int T = 0; T < NT; ++T) {
        const int  cur = T & 1;
        const char* Al = lds + cur * 65536;
        const char* Bl = Al + 32768;
        char*       An = lds + (cur ^ 1) * 65536;
        char*       Bn = An + 32768;
        const __hip_bfloat16* Asrc = Abase + (size_t)(T + 1) * 64;
        const __hip_bfloat16* Wsrc = Wbase + (size_t)(T + 1) * 64;
        const bool pf = (T + 1 < NT);

        auto lda = [&](int m, int kk) {   // m absolute 0..7 within wave rows
            const int row = (wr << 7) + (m << 4) + l15;
            const int ch  = ((kk << 2) + hi) ^ (row & 7);
            return *(const s16x8*)(Al + row * 128 + (ch << 4));
        };
        auto ldb = [&](int n, int kk) {
            const int row = (wc << 6) + (n << 4) + l15;
            const int ch  = ((kk << 2) + hi) ^ (row & 7);
            return *(const s16x8*)(Bl + row * 128 + (ch << 4));
        };

        // ---------- phase 0: Q(0,0)  [12 ds_read_b128]
        #pragma unroll
        for (int m = 0; m < 4; ++m) { afr[m][0] = lda(m, 0); afr[m][1] = lda(m, 1); }
        #pragma unroll
        for (int n = 0; n < 2; ++n) { bfr[n][0] = ldb(n, 0); bfr[n][1] = ldb(n, 1); }
        if (pf) stage_half(Asrc, An);
        __builtin_amdgcn_s_barrier();
        __builtin_amdgcn_s_setprio(1);
        #pragma unroll
        for (int kk = 0; kk < 2; ++kk)
            #pragma unroll
            for (int n = 0; n < 2; ++n)
                #pragma unroll
                for (int m = 0; m < 4; ++m)
                    acc[m][n] = __builtin_amdgcn_mfma_f32_16x16x32_bf16(
                        afr[m][kk], bfr[n][kk], acc[m][n], 0, 0, 0);
        __builtin_amdgcn_s_setprio(0);
        __builtin_amdgcn_s_barrier();

        // ---------- phase 1: Q(0,1)  [4 ds_read_b128]
        #pragma unroll
        for (int n = 0; n < 2; ++n) { bfr[2 + n][0] = ldb(2 + n, 0); bfr[2 + n][1] = ldb(2 + n, 1); }
        if (pf) stage_half(Asrc + (size_t)128 * K_, An + 16384);
        __builtin_amdgcn_s_barrier();
        __builtin_amdgcn_s_setprio(1);
        #pragma unroll
        for (int kk = 0; kk < 2; ++kk)
            #pragma unroll
            for (int n = 0; n < 2; ++n)
                #pragma unroll
                for (int m = 0; m < 4; ++m)
                    acc[m][2 + n] = __builtin_amdgcn_mfma_f32_16x16x32_bf16(
                        afr[m][kk], bfr[2 + n][kk], acc[m][2 + n], 0, 0, 0);
        __builtin_amdgcn_s_setprio(0);
        __builtin_amdgcn_s_barrier();

        // ---------- phase 2: Q(1,1)  [8 ds_read_b128]
        #pragma unroll
        for (int m = 0; m < 4; ++m) { afr[m][0] = lda(4 + m, 0); afr[m][1] = lda(4 + m, 1); }
        if (pf) stage_half(Wsrc, Bn);
        __builtin_amdgcn_s_barrier();
        __builtin_amdgcn_s_setprio(1);
        #pragma unroll
        for (int kk = 0; kk < 2; ++kk)
            #pragma unroll
            for (int n = 0; n < 2; ++n)
                #pragma unroll
                for (int m = 0; m < 4; ++m)
                    acc[4 + m][2 + n] = __builtin_amdgcn_mfma_f32_16x16x32_bf16(
                        afr[m][kk], bfr[2 + n][kk], acc[4 + m][2 + n], 0, 0, 0);
        __builtin_amdgcn_s_setprio(0);
        __builtin_amdgcn_s_barrier();

        // ---------- phase 3: Q(1,0)  [0 ds_read]
        if (pf) stage_half(Wsrc + (size_t)128 * K_, Bn + 16384);
        __builtin_amdgcn_s_barrier();
        __builtin_amdgcn_s_setprio(1);
        #pragma unroll
        for (int kk = 0; kk < 2; ++kk)
            #pragma unroll
            for (int n = 0; n < 2; ++n)
                #pragma unroll
                for (int m = 0; m < 4; ++m)
                    acc[4 + m][n] = __builtin_amdgcn_mfma_f32_16x16x32_bf16(
                        afr[m][kk], bfr[n][kk], acc[4 + m][n], 0, 0, 0);
        __builtin_amdgcn_s_setprio(0);
        __syncthreads();   // tile boundary: drains vmcnt (next buf valid)
    }

    // ---------- epilogue: scatter q/k/vT
    #pragma unroll
    for (int n = 0; n < 4; ++n) {
        const int col   = n0 + (wc << 6) + (n << 4) + l15;
        const int which = col >> 11;
        const int h     = (col >> 7) & 15;
        const int e     = col & 127;
        const float bn  = bias[col];
        #pragma unroll
        for (int m = 0; m < 8; ++m) {
            const int rowb = m0 + (wr << 7) + (m << 4) + (hi << 2);
            #pragma unroll
            for (int i = 0; i < 4; ++i) {
                const int mm = rowb + i;
                const int b  = mm >> 11;
                const int l  = mm & 2047;
                const __hip_bfloat16 val = __float2bfloat16(acc[m][n][i] + bn);
                if (which == 0)
                    q[((size_t)((b * H_ + h) * L_ + l) << 7) + e] = val;
                else if (which == 1)
                    k[((size_t)((b * H_ + h) * L_ + l) << 7) + e] = val;
                else
                    vT[(((size_t)(b * H_ + h) << 7) + e) * L_ + l] = val;
            }
        }
    }
}

// ---------------- bf16 MFMA GEMM (m97 structure), used for out-proj ---------
__global__ __launch_bounds__(256)
void gemm_bf16_nt(const __hip_bfloat16* __restrict__ A,
                  const __hip_bfloat16* __restrict__ W,
                  const float* __restrict__ bias,
                  float* __restrict__ o)
{
    __shared__ __hip_bfloat16 As[128 * 32];
    __shared__ __hip_bfloat16 Bs[128 * 32];

    const int t    = threadIdx.x;
    const int lane = t & 63;
    const int w    = t >> 6;
    const int l15  = lane & 15;
    const int hi   = lane >> 4;
    const int wr   = w >> 1, wc = w & 1;
    const int m0   = blockIdx.y << 7;
    const int n0   = blockIdx.x << 7;

    f32x4 acc[4][4];
    const f32x4 z4 = {0.f, 0.f, 0.f, 0.f};
    #pragma unroll
    for (int m = 0; m < 4; ++m)
        #pragma unroll
        for (int n = 0; n < 4; ++n) acc[m][n] = z4;

    const __hip_bfloat16* Ab = A + (size_t)m0 * K_;
    const __hip_bfloat16* Bb = W + (size_t)n0 * K_;
    const int srow = t >> 2;
    const int sc   = (t & 3) << 3;

    for (int k0 = 0; k0 < K_; k0 += 32) {
        #pragma unroll
        for (int j = 0; j < 2; ++j) {
            gld_lds16(Ab + (size_t)(j * 64 + srow) * K_ + k0 + sc,
                      (char*)As + j * 4096 + w * 1024);
            gld_lds16(Bb + (size_t)(j * 64 + srow) * K_ + k0 + sc,
                      (char*)Bs + j * 4096 + w * 1024);
        }
        __syncthreads();
        s16x8 af[4], bf[4];
        #pragma unroll
        for (int m = 0; m < 4; ++m)
            af[m] = *(const s16x8*)(As + (wr * 64 + m * 16 + l15) * 32 + hi * 8);
        #pragma unroll
        for (int n = 0; n < 4; ++n)
            bf[n] = *(const s16x8*)(Bs + (wc * 64 + n * 16 + l15) * 32 + hi * 8);
        #pragma unroll
        for (int m = 0; m < 4; ++m)
            #pragma unroll
            for (int n = 0; n < 4; ++n)
                acc[m][n] = __builtin_amdgcn_mfma_f32_16x16x32_bf16(af[m], bf[n], acc[m][n], 0, 0, 0);
        __syncthreads();
    }

    #pragma unroll
    for (int n = 0; n < 4; ++n) {
        const int col = n0 + wc * 64 + n * 16 + l15;
        const float bn = bias[col];
        #pragma unroll
        for (int m = 0; m < 4; ++m) {
            const int rowb = m0 + wr * 64 + m * 16 + hi * 4;
            #pragma unroll
            for (int i = 0; i < 4; ++i)
                o[(size_t)(rowb + i) * D_ + col] = acc[m][n][i] + bn;
        }
    }
}

// ---------------- bf16 MFMA causal flash attention (R5, unchanged) ----------
__global__ __launch_bounds__(256)
void attn_mfma(const __hip_bfloat16* __restrict__ Qg,
               const __hip_bfloat16* __restrict__ Kg,
               const __hip_bfloat16* __restrict__ vTg,
               __hip_bfloat16* __restrict__ O)
{
    __shared__ __hip_bfloat16 Ks[2][64 * 128];
    __shared__ __hip_bfloat16 Vt[2][128 * 64];
    __shared__ __hip_bfloat16 Ps[4 * 1024];

    const int t    = threadIdx.x;
    const int lane = t & 63;
    const int w    = t >> 6;
    const int l15  = lane & 15;
    const int hi   = lane >> 4;
    const int pq   = blockIdx.x;
    const int bh   = blockIdx.y;
    const size_t base = (size_t)bh * (L_ * E_);
    const float scale = 0.08838834764831843f;
    const int krow = t >> 4;
    const int kc16 = t & 15;

    const __hip_bfloat16* Kbh  = Kg  + base;
    const __hip_bfloat16* vTbh = vTg + base;

    auto stage = [&](int kt2, int buf) {
        const __hip_bfloat16* Kb = Kbh + ((size_t)(kt2 << 6)) * E_;
        char* kd = (char*)Ks + buf * 16384 + (w << 10);
        #pragma unroll
        for (int j = 0; j < 4; ++j) {
            const int row = (j << 4) + krow;
            const int csw = kc16 ^ (row & 7);
            gld_lds16(Kb + (size_t)row * E_ + (csw << 3), kd + (j << 12));
        }
        const __hip_bfloat16* Vb = vTbh + (kt2 << 6);
        char* vd = (char*)Vt + buf * 16384 + (w << 10);
        #pragma unroll
        for (int j = 0; j < 4; ++j) {
            const int e  = (j << 5) + (t >> 3);
            const int g8 = (t & 7) ^ (e & 7);
            gld_lds16(Vb + (size_t)e * L_ + (g8 << 3), vd + (j << 12));
        }
    };

    const f32x4 z4 = {0.f, 0.f, 0.f, 0.f};

    #pragma unroll 1
    for (int seg = 0; seg < 2; ++seg) {
        const int qt = seg ? pq : 31 - pq;
        const int q0 = (qt << 6) + (w << 4);

        s16x8 qf[4];
        #pragma unroll
        for (int e0 = 0; e0 < 4; ++e0)
            qf[e0] = *(const s16x8*)(Qg + base + (size_t)(q0 + l15) * E_ + e0 * 32 + hi * 8);

        f32x4 oacc[8];
        #pragma unroll
        for (int ef = 0; ef < 8; ++ef) oacc[ef] = z4;
        float mrow[4] = {-1e30f, -1e30f, -1e30f, -1e30f};
        float lrow[4] = {0.f, 0.f, 0.f, 0.f};

        stage(0, 0);
        __syncthreads();

        for (int kt = 0; kt <= qt; ++kt) {
            const int cur = kt & 1;
            if (kt < qt) stage(kt + 1, cur ^ 1);

            const char* Ksc = (const char*)Ks + cur * 16384;
            const char* Vtc = (const char*)Vt + cur * 16384;

            f32x4 sf[4];
            #pragma unroll
            for (int c = 0; c < 4; ++c) {
                f32x4 s = z4;
                const int row = (c << 4) + l15;
                #pragma unroll
                for (int e0 = 0; e0 < 4; ++e0) {
                    const int ch = ((e0 << 2) + hi) ^ (row & 7);
                    const s16x8 kf = *(const s16x8*)(Ksc + (row << 8) + (ch << 4));
                    s = __builtin_amdgcn_mfma_f32_16x16x32_bf16(qf[e0], kf, s, 0, 0, 0);
                }
                sf[c] = s;
            }

            float p4[4][4];
            float tmax[4] = {-1e30f, -1e30f, -1e30f, -1e30f};
            if (kt == qt) {
                const int qg = q0 + (hi << 2);
                #pragma unroll
                for (int c = 0; c < 4; ++c) {
                    const int kvg = (kt << 6) + (c << 4) + l15;
                    #pragma unroll
                    for (int i = 0; i < 4; ++i) {
                        float s = sf[c][i] * scale;
                        if (kvg > qg + i) s = -1e30f;
                        p4[c][i] = s;
                        tmax[i] = fmaxf(tmax[i], s);
                    }
                }
            } else {
                #pragma unroll
                for (int c = 0; c < 4; ++c)
                    #pragma unroll
                    for (int i = 0; i < 4; ++i) {
                        const float s = sf[c][i] * scale;
                        p4[c][i] = s;
                        tmax[i] = fmaxf(tmax[i], s);
                    }
            }
            float fsc[4];
            #pragma unroll
            for (int i = 0; i < 4; ++i) {
                float v = tmax[i];
                v = fmaxf(v, __shfl_xor(v, 1));
                v = fmaxf(v, __shfl_xor(v, 2));
                v = fmaxf(v, __shfl_xor(v, 4));
                v = fmaxf(v, __shfl_xor(v, 8));
                const float mnew = fmaxf(mrow[i], v);
                fsc[i] = __expf(mrow[i] - mnew);
                mrow[i] = mnew;
                float sum = 0.f;
                #pragma unroll
                for (int c = 0; c < 4; ++c) {
                    const float pe = __expf(p4[c][i] - mnew);
                    p4[c][i] = pe;
                    sum += pe;
                }
                sum += __shfl_xor(sum, 1);
                sum += __shfl_xor(sum, 2);
                sum += __shfl_xor(sum, 4);
                sum += __shfl_xor(sum, 8);
                lrow[i] = lrow[i] * fsc[i] + sum;
            }
            #pragma unroll
            for (int ef = 0; ef < 8; ++ef)
                #pragma unroll
                for (int i = 0; i < 4; ++i) oacc[ef][i] *= fsc[i];

            #pragma unroll
            for (int c = 0; c < 4; ++c)
                #pragma unroll
                for (int i = 0; i < 4; ++i) {
                    const int r   = (hi << 2) + i;
                    const int col = (c << 4) + l15;
                    const int ch  = (col >> 3) ^ (r & 7);
                    const int by  = (r << 7) + ((ch << 4) | ((col & 7) << 1));
                    *(__hip_bfloat16*)((char*)Ps + (w << 11) + by) = __float2bfloat16(p4[c][i]);
                }
            asm volatile("s_waitcnt lgkmcnt(0)" ::: "memory");

            #pragma unroll
            for (int kh = 0; kh < 2; ++kh) {
                const int chp = ((kh << 2) + hi) ^ (l15 & 7);
                const s16x8 pa = *(const s16x8*)((char*)Ps + (w << 11) + (l15 << 7) + (chp << 4));
                #pragma unroll
                for (int ef = 0; ef < 8; ++ef) {
                    const int e   = (ef << 4) + l15;
                    const int chv = ((kh << 2) + hi) ^ (e & 7);
                    const s16x8 vb = *(const s16x8*)(Vtc + (e << 7) + (chv << 4));
                    oacc[ef] = __builtin_amdgcn_mfma_f32_16x16x32_bf16(pa, vb, oacc[ef], 0, 0, 0);
                }
            }
            __syncthreads();
        }

        const int b = bh >> 4, h = bh & 15;
        float invl[4];
        #pragma unroll
        for (int i = 0; i < 4; ++i) invl[i] = 1.f / lrow[i];
        #pragma unroll
        for (int ef = 0; ef < 8; ++ef) {
            const int e = (ef << 4) + l15;
            #pragma unroll
            for (int i = 0; i < 4; ++i) {
                const int row = q0 + (hi << 2) + i;
                O[((size_t)(b * L_ + row) * D_) + (h << 7) + e] =
                    __float2bfloat16(oacc[ef][i] * invl[i]);
            }
        }
    }
}

extern "C" void kernel_launch(void* const* d_in, const int* in_sizes, int n_in,
                              void* d_out, int out_size, void* d_ws, size_t ws_size,
                              hipStream_t stream)
{
    const float* x    = (const float*)d_in[0];
    const float* Wqkv = (const float*)d_in[1];
    const float* bqkv = (const float*)d_in[2];
    const float* Wout = (const float*)d_in[3];
    const float* bout = (const float*)d_in[4];
    float* out = (float*)d_out;

    __hip_bfloat16* xb  = (__hip_bfloat16*)d_ws;
    __hip_bfloat16* wqb = xb  + (size_t)M_ * K_;
    __hip_bfloat16* wob = wqb + (size_t)N3_ * K_;
    __hip_bfloat16* qb  = wob + (size_t)D_ * K_;
    __hip_bfloat16* kb  = qb  + (size_t)M_ * D_;
    __hip_bfloat16* vtb = kb  + (size_t)M_ * D_;   // vT[b,h,e,l]
    __hip_bfloat16* aob = vtb + (size_t)M_ * D_;

    cast_bf16<<<(M_ * K_ / 8) / 256, 256, 0, stream>>>(x, xb, M_ * K_ / 8);
    cast_bf16<<<(N3_ * K_ / 8) / 256, 256, 0, stream>>>(Wqkv, wqb, N3_ * K_ / 8);
    cast_bf16<<<(D_ * K_ / 8) / 256, 256, 0, stream>>>(Wout, wob, D_ * K_ / 8);

    dim3 g1(N3_ / 256, M_ / 256);   // 24 x 16 = 384 blocks
    gemm_qkv_8ph<<<g1, dim3(512), 0, stream>>>(xb, wqb, bqkv, qb, kb, vtb);

    dim3 g2(16, B_ * H_);           // paired q-tiles
    attn_mfma<<<g2, dim3(256), 0, stream>>>(qb, kb, vtb, aob);

    dim3 g3(D_ / 128, M_ / 128);    // 16 x 32
    gemm_bf16_nt<<<g3, dim3(256), 0, stream>>>(aob, wob, bout, out);
}

// Round 7
// 422.489 us; speedup vs baseline: 7.3348x; 1.0116x over previous
//
#include <hip/hip_runtime.h>
#include <hip/hip_bf16.h>

#define B_ 2
#define L_ 2048
#define D_ 2048
#define H_ 16
#define E_ 128
#define M_ 4096
#define K_ 2048
#define N3_ 6144

typedef __attribute__((ext_vector_type(4))) float f32x4;
typedef short s16x8 __attribute__((ext_vector_type(8)));   // 8 bf16 = 4 VGPRs

__device__ inline void gld_lds16(const void* g, void* l) {
    __builtin_amdgcn_global_load_lds(
        (const __attribute__((address_space(1))) void*)g,
        (__attribute__((address_space(3))) void*)l, 16, 0, 0);
}

// ---------------- fp32 -> bf16 cast (vectorized) ----------------------------
__global__ __launch_bounds__(256)
void cast_bf16(const float* __restrict__ in, __hip_bfloat16* __restrict__ out, int n8)
{
    const int i = blockIdx.x * 256 + threadIdx.x;
    if (i >= n8) return;
    const float4 a = ((const float4*)in)[2 * i];
    const float4 b = ((const float4*)in)[2 * i + 1];
    union { __hip_bfloat16 h[8]; uint4 u; } o;
    o.h[0] = __float2bfloat16(a.x); o.h[1] = __float2bfloat16(a.y);
    o.h[2] = __float2bfloat16(a.z); o.h[3] = __float2bfloat16(a.w);
    o.h[4] = __float2bfloat16(b.x); o.h[5] = __float2bfloat16(b.y);
    o.h[6] = __float2bfloat16(b.z); o.h[7] = __float2bfloat16(b.w);
    ((uint4*)out)[i] = o.u;
}

// ======== 256x256 8-phase bf16 GEMM (QKV), counted-vmcnt pipeline ===========
// 512 thr (8 waves), BK=64, dbuf LDS 128 KiB, XOR chunk swizzle (0 conflicts,
// verified R6). Phases iterate global C-quadrants (0,0),(0,1),(1,1),(1,0):
// every wave reads ONE A-half + ONE B-half per phase -> counted vmcnt works.
// Stage order per tile: A0,B0,A1,B1 (one half-tile/phase, 1 tile ahead).
// Waits: vmcnt(2) end-ph0, vmcnt(4) end-ph3, each BEFORE the closing barrier
// (barrier collectivizes per-wave waits). Never vmcnt(0) in steady state.
__global__ __launch_bounds__(512, 2)
void gemm_qkv_8ph(const __hip_bfloat16* __restrict__ A,
                  const __hip_bfloat16* __restrict__ W,
                  const float* __restrict__ bias,
                  __hip_bfloat16* __restrict__ q,
                  __hip_bfloat16* __restrict__ k,
                  __hip_bfloat16* __restrict__ vT)
{
    __shared__ char lds[131072];   // [buf][A0|A1 32KB | B0|B1 32KB]

    const int t    = threadIdx.x;
    const int lane = t & 63;
    const int w    = t >> 6;      // 0..7
    const int l15  = lane & 15;
    const int hi   = lane >> 4;
    const int wr   = w >> 2;      // 0..1: 64-row slice within 128-row half
    const int wc   = w & 3;       // 0..3: 32-col slice within 128-col half
    const int n0   = blockIdx.x << 8;
    const int m0   = blockIdx.y << 8;

    f32x4 acc[2][2][4][2];        // [qr][qc][m][n]
    const f32x4 z4 = {0.f, 0.f, 0.f, 0.f};
    #pragma unroll
    for (int qr = 0; qr < 2; ++qr)
        #pragma unroll
        for (int qc = 0; qc < 2; ++qc)
            #pragma unroll
            for (int m = 0; m < 4; ++m)
                #pragma unroll
                for (int n = 0; n < 2; ++n) acc[qr][qc][m][n] = z4;

    s16x8 afr[4][2];      // A fragments of current A-half
    s16x8 bfr0[2][2];     // B fragments, half 0
    s16x8 bfr1[2][2];     // B fragments, half 1

    const __hip_bfloat16* Abase = A + (size_t)m0 * K_;
    const __hip_bfloat16* Wbase = W + (size_t)n0 * K_;

    // stage one 128x64 half-tile (2 vmem ops/thread): linear LDS dest,
    // inverse-swizzled global source (involution verified R6: 0 conflicts)
    auto stage_half = [&](const __hip_bfloat16* src, char* dst) {
        #pragma unroll
        for (int i = 0; i < 2; ++i) {
            const int slot = (i << 9) + t;          // 0..1023
            const int row  = slot >> 3;             // 0..127
            const int csw  = (slot & 7) ^ (row & 7);
            gld_lds16(src + (size_t)row * K_ + (csw << 3),
                      dst + (i << 13) + (w << 10));
        }
    };

    // prologue: tile 0 -> buf 0, order A0,B0,A1,B1 (matches steady state)
    stage_half(Abase,                     lds);
    stage_half(Wbase,                     lds + 32768);
    stage_half(Abase + (size_t)128 * K_,  lds + 16384);
    stage_half(Wbase + (size_t)128 * K_,  lds + 49152);
    asm volatile("s_waitcnt vmcnt(4)" ::: "memory");   // A0,B0 done
    __builtin_amdgcn_s_barrier();

    const int NT = K_ / 64;   // 32
    for (int T = 0; T < NT; ++T) {
        const int  cur = T & 1;
        const char* Al = lds + cur * 65536;            // A halves: +0 / +16384
        const char* Bl = Al + 32768;                   // B halves: +0 / +16384
        char*       An = lds + (cur ^ 1) * 65536;
        char*       Bn = An + 32768;
        const __hip_bfloat16* Asrc = Abase + (size_t)(T + 1) * 64;
        const __hip_bfloat16* Wsrc = Wbase + (size_t)(T + 1) * 64;
        const bool pf = (T + 1 < NT);

        auto lda = [&](const char* half, int m, int kk) {
            const int r  = (wr << 6) + (m << 4) + l15;          // 0..127
            const int ch = ((kk << 2) + hi) ^ (r & 7);
            return *(const s16x8*)(half + r * 128 + (ch << 4));
        };
        auto ldb = [&](const char* half, int n, int kk) {
            const int r  = (wc << 5) + (n << 4) + l15;          // 0..127
            const int ch = ((kk << 2) + hi) ^ (r & 7);
            return *(const s16x8*)(half + r * 128 + (ch << 4));
        };

        // ---------- phase 0: Q(0,0) — read A0,B0 [12 ds_read_b128]
        #pragma unroll
        for (int m = 0; m < 4; ++m) { afr[m][0]  = lda(Al, m, 0);      afr[m][1]  = lda(Al, m, 1); }
        #pragma unroll
        for (int n = 0; n < 2; ++n) { bfr0[n][0] = ldb(Bl, n, 0);      bfr0[n][1] = ldb(Bl, n, 1); }
        if (pf) stage_half(Asrc, An);                  // A0'
        __builtin_amdgcn_s_barrier();
        __builtin_amdgcn_s_setprio(1);
        #pragma unroll
        for (int kk = 0; kk < 2; ++kk)
            #pragma unroll
            for (int n = 0; n < 2; ++n)
                #pragma unroll
                for (int m = 0; m < 4; ++m)
                    acc[0][0][m][n] = __builtin_amdgcn_mfma_f32_16x16x32_bf16(
                        afr[m][kk], bfr0[n][kk], acc[0][0][m][n], 0, 0, 0);
        __builtin_amdgcn_s_setprio(0);
        if (pf) asm volatile("s_waitcnt vmcnt(2)" ::: "memory");  // A1,B1 done
        else    asm volatile("s_waitcnt vmcnt(0)" ::: "memory");
        __builtin_amdgcn_s_barrier();

        // ---------- phase 1: Q(0,1) — read B1 [4 ds_read_b128]
        #pragma unroll
        for (int n = 0; n < 2; ++n) { bfr1[n][0] = ldb(Bl + 16384, n, 0); bfr1[n][1] = ldb(Bl + 16384, n, 1); }
        if (pf) stage_half(Wsrc, Bn);                  // B0'
        __builtin_amdgcn_s_barrier();
        __builtin_amdgcn_s_setprio(1);
        #pragma unroll
        for (int kk = 0; kk < 2; ++kk)
            #pragma unroll
            for (int n = 0; n < 2; ++n)
                #pragma unroll
                for (int m = 0; m < 4; ++m)
                    acc[0][1][m][n] = __builtin_amdgcn_mfma_f32_16x16x32_bf16(
                        afr[m][kk], bfr1[n][kk], acc[0][1][m][n], 0, 0, 0);
        __builtin_amdgcn_s_setprio(0);
        __builtin_amdgcn_s_barrier();

        // ---------- phase 2: Q(1,1) — read A1 [8 ds_read_b128]
        #pragma unroll
        for (int m = 0; m < 4; ++m) { afr[m][0] = lda(Al + 16384, m, 0); afr[m][1] = lda(Al + 16384, m, 1); }
        if (pf) stage_half(Asrc + (size_t)128 * K_, An + 16384);   // A1'
        __builtin_amdgcn_s_barrier();
        __builtin_amdgcn_s_setprio(1);
        #pragma unroll
        for (int kk = 0; kk < 2; ++kk)
            #pragma unroll
            for (int n = 0; n < 2; ++n)
                #pragma unroll
                for (int m = 0; m < 4; ++m)
                    acc[1][1][m][n] = __builtin_amdgcn_mfma_f32_16x16x32_bf16(
                        afr[m][kk], bfr1[n][kk], acc[1][1][m][n], 0, 0, 0);
        __builtin_amdgcn_s_setprio(0);
        __builtin_amdgcn_s_barrier();

        // ---------- phase 3: Q(1,0) — no ds_read (reuse afr=A1, bfr0)
        if (pf) stage_half(Wsrc + (size_t)128 * K_, Bn + 16384);   // B1'
        __builtin_amdgcn_s_barrier();
        __builtin_amdgcn_s_setprio(1);
        #pragma unroll
        for (int kk = 0; kk < 2; ++kk)
            #pragma unroll
            for (int n = 0; n < 2; ++n)
                #pragma unroll
                for (int m = 0; m < 4; ++m)
                    acc[1][0][m][n] = __builtin_amdgcn_mfma_f32_16x16x32_bf16(
                        afr[m][kk], bfr0[n][kk], acc[1][0][m][n], 0, 0, 0);
        __builtin_amdgcn_s_setprio(0);
        if (pf) asm volatile("s_waitcnt vmcnt(4)" ::: "memory");  // next A0,B0 done
        __builtin_amdgcn_s_barrier();
    }

    // ---------- epilogue: scatter q/k/vT
    #pragma unroll
    for (int qc = 0; qc < 2; ++qc)
        #pragma unroll
        for (int n = 0; n < 2; ++n) {
            const int col   = n0 + (qc << 7) + (wc << 5) + (n << 4) + l15;
            const int which = col >> 11;
            const int h     = (col >> 7) & 15;
            const int e     = col & 127;
            const float bn  = bias[col];
            #pragma unroll
            for (int qr = 0; qr < 2; ++qr)
                #pragma unroll
                for (int m = 0; m < 4; ++m) {
                    const int rowb = m0 + (qr << 7) + (wr << 6) + (m << 4) + (hi << 2);
                    #pragma unroll
                    for (int i = 0; i < 4; ++i) {
                        const int mm = rowb + i;
                        const int b  = mm >> 11;
                        const int l  = mm & 2047;
                        const __hip_bfloat16 val = __float2bfloat16(acc[qr][qc][m][n][i] + bn);
                        if (which == 0)
                            q[((size_t)((b * H_ + h) * L_ + l) << 7) + e] = val;
                        else if (which == 1)
                            k[((size_t)((b * H_ + h) * L_ + l) << 7) + e] = val;
                        else
                            vT[(((size_t)(b * H_ + h) << 7) + e) * L_ + l] = val;
                    }
                }
        }
}

// ---------------- bf16 MFMA GEMM (m97 structure), used for out-proj ---------
__global__ __launch_bounds__(256)
void gemm_bf16_nt(const __hip_bfloat16* __restrict__ A,
                  const __hip_bfloat16* __restrict__ W,
                  const float* __restrict__ bias,
                  float* __restrict__ o)
{
    __shared__ __hip_bfloat16 As[128 * 32];
    __shared__ __hip_bfloat16 Bs[128 * 32];

    const int t    = threadIdx.x;
    const int lane = t & 63;
    const int w    = t >> 6;
    const int l15  = lane & 15;
    const int hi   = lane >> 4;
    const int wr   = w >> 1, wc = w & 1;
    const int m0   = blockIdx.y << 7;
    const int n0   = blockIdx.x << 7;

    f32x4 acc[4][4];
    const f32x4 z4 = {0.f, 0.f, 0.f, 0.f};
    #pragma unroll
    for (int m = 0; m < 4; ++m)
        #pragma unroll
        for (int n = 0; n < 4; ++n) acc[m][n] = z4;

    const __hip_bfloat16* Ab = A + (size_t)m0 * K_;
    const __hip_bfloat16* Bb = W + (size_t)n0 * K_;
    const int srow = t >> 2;
    const int sc   = (t & 3) << 3;

    for (int k0 = 0; k0 < K_; k0 += 32) {
        #pragma unroll
        for (int j = 0; j < 2; ++j) {
            gld_lds16(Ab + (size_t)(j * 64 + srow) * K_ + k0 + sc,
                      (char*)As + j * 4096 + w * 1024);
            gld_lds16(Bb + (size_t)(j * 64 + srow) * K_ + k0 + sc,
                      (char*)Bs + j * 4096 + w * 1024);
        }
        __syncthreads();
        s16x8 af[4], bf[4];
        #pragma unroll
        for (int m = 0; m < 4; ++m)
            af[m] = *(const s16x8*)(As + (wr * 64 + m * 16 + l15) * 32 + hi * 8);
        #pragma unroll
        for (int n = 0; n < 4; ++n)
            bf[n] = *(const s16x8*)(Bs + (wc * 64 + n * 16 + l15) * 32 + hi * 8);
        #pragma unroll
        for (int m = 0; m < 4; ++m)
            #pragma unroll
            for (int n = 0; n < 4; ++n)
                acc[m][n] = __builtin_amdgcn_mfma_f32_16x16x32_bf16(af[m], bf[n], acc[m][n], 0, 0, 0);
        __syncthreads();
    }

    #pragma unroll
    for (int n = 0; n < 4; ++n) {
        const int col = n0 + wc * 64 + n * 16 + l15;
        const float bn = bias[col];
        #pragma unroll
        for (int m = 0; m < 4; ++m) {
            const int rowb = m0 + wr * 64 + m * 16 + hi * 4;
            #pragma unroll
            for (int i = 0; i < 4; ++i)
                o[(size_t)(rowb + i) * D_ + col] = acc[m][n][i] + bn;
        }
    }
}

// ---------------- bf16 MFMA causal flash attention (unchanged) --------------
__global__ __launch_bounds__(256)
void attn_mfma(const __hip_bfloat16* __restrict__ Qg,
               const __hip_bfloat16* __restrict__ Kg,
               const __hip_bfloat16* __restrict__ vTg,
               __hip_bfloat16* __restrict__ O)
{
    __shared__ __hip_bfloat16 Ks[2][64 * 128];
    __shared__ __hip_bfloat16 Vt[2][128 * 64];
    __shared__ __hip_bfloat16 Ps[4 * 1024];

    const int t    = threadIdx.x;
    const int lane = t & 63;
    const int w    = t >> 6;
    const int l15  = lane & 15;
    const int hi   = lane >> 4;
    const int pq   = blockIdx.x;
    const int bh   = blockIdx.y;
    const size_t base = (size_t)bh * (L_ * E_);
    const float scale = 0.08838834764831843f;
    const int krow = t >> 4;
    const int kc16 = t & 15;

    const __hip_bfloat16* Kbh  = Kg  + base;
    const __hip_bfloat16* vTbh = vTg + base;

    auto stage = [&](int kt2, int buf) {
        const __hip_bfloat16* Kb = Kbh + ((size_t)(kt2 << 6)) * E_;
        char* kd = (char*)Ks + buf * 16384 + (w << 10);
        #pragma unroll
        for (int j = 0; j < 4; ++j) {
            const int row = (j << 4) + krow;
            const int csw = kc16 ^ (row & 7);
            gld_lds16(Kb + (size_t)row * E_ + (csw << 3), kd + (j << 12));
        }
        const __hip_bfloat16* Vb = vTbh + (kt2 << 6);
        char* vd = (char*)Vt + buf * 16384 + (w << 10);
        #pragma unroll
        for (int j = 0; j < 4; ++j) {
            const int e  = (j << 5) + (t >> 3);
            const int g8 = (t & 7) ^ (e & 7);
            gld_lds16(Vb + (size_t)e * L_ + (g8 << 3), vd + (j << 12));
        }
    };

    const f32x4 z4 = {0.f, 0.f, 0.f, 0.f};

    #pragma unroll 1
    for (int seg = 0; seg < 2; ++seg) {
        const int qt = seg ? pq : 31 - pq;
        const int q0 = (qt << 6) + (w << 4);

        s16x8 qf[4];
        #pragma unroll
        for (int e0 = 0; e0 < 4; ++e0)
            qf[e0] = *(const s16x8*)(Qg + base + (size_t)(q0 + l15) * E_ + e0 * 32 + hi * 8);

        f32x4 oacc[8];
        #pragma unroll
        for (int ef = 0; ef < 8; ++ef) oacc[ef] = z4;
        float mrow[4] = {-1e30f, -1e30f, -1e30f, -1e30f};
        float lrow[4] = {0.f, 0.f, 0.f, 0.f};

        stage(0, 0);
        __syncthreads();

        for (int kt = 0; kt <= qt; ++kt) {
            const int cur = kt & 1;
            if (kt < qt) stage(kt + 1, cur ^ 1);

            const char* Ksc = (const char*)Ks + cur * 16384;
            const char* Vtc = (const char*)Vt + cur * 16384;

            f32x4 sf[4];
            #pragma unroll
            for (int c = 0; c < 4; ++c) {
                f32x4 s = z4;
                const int row = (c << 4) + l15;
                #pragma unroll
                for (int e0 = 0; e0 < 4; ++e0) {
                    const int ch = ((e0 << 2) + hi) ^ (row & 7);
                    const s16x8 kf = *(const s16x8*)(Ksc + (row << 8) + (ch << 4));
                    s = __builtin_amdgcn_mfma_f32_16x16x32_bf16(qf[e0], kf, s, 0, 0, 0);
                }
                sf[c] = s;
            }

            float p4[4][4];
            float tmax[4] = {-1e30f, -1e30f, -1e30f, -1e30f};
            if (kt == qt) {
                const int qg = q0 + (hi << 2);
                #pragma unroll
                for (int c = 0; c < 4; ++c) {
                    const int kvg = (kt << 6) + (c << 4) + l15;
                    #pragma unroll
                    for (int i = 0; i < 4; ++i) {
                        float s = sf[c][i] * scale;
                        if (kvg > qg + i) s = -1e30f;
                        p4[c][i] = s;
                        tmax[i] = fmaxf(tmax[i], s);
                    }
                }
            } else {
                #pragma unroll
                for (int c = 0; c < 4; ++c)
                    #pragma unroll
                    for (int i = 0; i < 4; ++i) {
                        const float s = sf[c][i] * scale;
                        p4[c][i] = s;
                        tmax[i] = fmaxf(tmax[i], s);
                    }
            }
            float fsc[4];
            #pragma unroll
            for (int i = 0; i < 4; ++i) {
                float v = tmax[i];
                v = fmaxf(v, __shfl_xor(v, 1));
                v = fmaxf(v, __shfl_xor(v, 2));
                v = fmaxf(v, __shfl_xor(v, 4));
                v = fmaxf(v, __shfl_xor(v, 8));
                const float mnew = fmaxf(mrow[i], v);
                fsc[i] = __expf(mrow[i] - mnew);
                mrow[i] = mnew;
                float sum = 0.f;
                #pragma unroll
                for (int c = 0; c < 4; ++c) {
                    const float pe = __expf(p4[c][i] - mnew);
                    p4[c][i] = pe;
                    sum += pe;
                }
                sum += __shfl_xor(sum, 1);
                sum += __shfl_xor(sum, 2);
                sum += __shfl_xor(sum, 4);
                sum += __shfl_xor(sum, 8);
                lrow[i] = lrow[i] * fsc[i] + sum;
            }
            #pragma unroll
            for (int ef = 0; ef < 8; ++ef)
                #pragma unroll
                for (int i = 0; i < 4; ++i) oacc[ef][i] *= fsc[i];

            #pragma unroll
            for (int c = 0; c < 4; ++c)
                #pragma unroll
                for (int i = 0; i < 4; ++i) {
                    const int r   = (hi << 2) + i;
                    const int col = (c << 4) + l15;
                    const int ch  = (col >> 3) ^ (r & 7);
                    const int by  = (r << 7) + ((ch << 4) | ((col & 7) << 1));
                    *(__hip_bfloat16*)((char*)Ps + (w << 11) + by) = __float2bfloat16(p4[c][i]);
                }
            asm volatile("s_waitcnt lgkmcnt(0)" ::: "memory");

            #pragma unroll
            for (int kh = 0; kh < 2; ++kh) {
                const int chp = ((kh << 2) + hi) ^ (l15 & 7);
                const s16x8 pa = *(const s16x8*)((char*)Ps + (w << 11) + (l15 << 7) + (chp << 4));
                #pragma unroll
                for (int ef = 0; ef < 8; ++ef) {
                    const int e   = (ef << 4) + l15;
                    const int chv = ((kh << 2) + hi) ^ (e & 7);
                    const s16x8 vb = *(const s16x8*)(Vtc + (e << 7) + (chv << 4));
                    oacc[ef] = __builtin_amdgcn_mfma_f32_16x16x32_bf16(pa, vb, oacc[ef], 0, 0, 0);
                }
            }
            __syncthreads();
        }

        const int b = bh >> 4, h = bh & 15;
        float invl[4];
        #pragma unroll
        for (int i = 0; i < 4; ++i) invl[i] = 1.f / lrow[i];
        #pragma unroll
        for (int ef = 0; ef < 8; ++ef) {
            const int e = (ef << 4) + l15;
            #pragma unroll
            for (int i = 0; i < 4; ++i) {
                const int row = q0 + (hi << 2) + i;
                O[((size_t)(b * L_ + row) * D_) + (h << 7) + e] =
                    __float2bfloat16(oacc[ef][i] * invl[i]);
            }
        }
    }
}

extern "C" void kernel_launch(void* const* d_in, const int* in_sizes, int n_in,
                              void* d_out, int out_size, void* d_ws, size_t ws_size,
                              hipStream_t stream)
{
    const float* x    = (const float*)d_in[0];
    const float* Wqkv = (const float*)d_in[1];
    const float* bqkv = (const float*)d_in[2];
    const float* Wout = (const float*)d_in[3];
    const float* bout = (const float*)d_in[4];
    float* out = (float*)d_out;

    __hip_bfloat16* xb  = (__hip_bfloat16*)d_ws;
    __hip_bfloat16* wqb = xb  + (size_t)M_ * K_;
    __hip_bfloat16* wob = wqb + (size_t)N3_ * K_;
    __hip_bfloat16* qb  = wob + (size_t)D_ * K_;
    __hip_bfloat16* kb  = qb  + (size_t)M_ * D_;
    __hip_bfloat16* vtb = kb  + (size_t)M_ * D_;   // vT[b,h,e,l]
    __hip_bfloat16* aob = vtb + (size_t)M_ * D_;

    cast_bf16<<<(M_ * K_ / 8) / 256, 256, 0, stream>>>(x, xb, M_ * K_ / 8);
    cast_bf16<<<(N3_ * K_ / 8) / 256, 256, 0, stream>>>(Wqkv, wqb, N3_ * K_ / 8);
    cast_bf16<<<(D_ * K_ / 8) / 256, 256, 0, stream>>>(Wout, wob, D_ * K_ / 8);

    dim3 g1(N3_ / 256, M_ / 256);   // 24 x 16 = 384 blocks
    gemm_qkv_8ph<<<g1, dim3(512), 0, stream>>>(xb, wqb, bqkv, qb, kb, vtb);

    dim3 g2(16, B_ * H_);           // paired q-tiles
    attn_mfma<<<g2, dim3(256), 0, stream>>>(qb, kb, vtb, aob);

    dim3 g3(D_ / 128, M_ / 128);    // 16 x 32
    gemm_bf16_nt<<<g3, dim3(256), 0, stream>>>(aob, wob, bout, out);
}

// Round 10
// 389.944 us; speedup vs baseline: 7.9470x; 1.0835x over previous
//
#include <hip/hip_runtime.h>
#include <hip/hip_bf16.h>

#define B_ 2
#define L_ 2048
#define D_ 2048
#define H_ 16
#define E_ 128
#define M_ 4096
#define K_ 2048
#define N3_ 6144

typedef __attribute__((ext_vector_type(4))) float f32x4;
typedef short s16x8 __attribute__((ext_vector_type(8)));   // 8 bf16 = 4 VGPRs

__device__ inline void gld_lds16(const void* g, void* l) {
    __builtin_amdgcn_global_load_lds(
        (const __attribute__((address_space(1))) void*)g,
        (__attribute__((address_space(3))) void*)l, 16, 0, 0);
}

// ---------------- fp32 -> bf16 cast, all three tensors in one launch --------
__global__ __launch_bounds__(256)
void cast3_bf16(const float* __restrict__ a, __hip_bfloat16* __restrict__ ao, int na,
                const float* __restrict__ b, __hip_bfloat16* __restrict__ bo, int nb,
                const float* __restrict__ c, __hip_bfloat16* __restrict__ co, int nc)
{
    const int i = blockIdx.x * 256 + threadIdx.x;
    const float* in; __hip_bfloat16* out; int j;
    if (i < na)                { in = a; out = ao; j = i; }
    else if (i < na + nb)      { in = b; out = bo; j = i - na; }
    else if (i < na + nb + nc) { in = c; out = co; j = i - na - nb; }
    else return;
    const float4 x = ((const float4*)in)[2 * j];
    const float4 y = ((const float4*)in)[2 * j + 1];
    union { __hip_bfloat16 h[8]; uint4 u; } o;
    o.h[0] = __float2bfloat16(x.x); o.h[1] = __float2bfloat16(x.y);
    o.h[2] = __float2bfloat16(x.z); o.h[3] = __float2bfloat16(x.w);
    o.h[4] = __float2bfloat16(y.x); o.h[5] = __float2bfloat16(y.y);
    o.h[6] = __float2bfloat16(y.z); o.h[7] = __float2bfloat16(y.w);
    ((uint4*)out)[j] = o.u;
}

// ======== 128x256 2-phase bf16 GEMM, counted-vmcnt pipeline =================
// 512 thr (8 waves, 2x4), BK=64, dbuf LDS 96 KiB (A 16K | B0 16K | B1 16K),
// XOR chunk swizzle (0 conflicts, verified R6/R7). Phase = N-half: ph0 reads
// A + B0 (12 ds_read_b128), ph1 reads B1 (4). Stage: ph0 issues A',B0' (4
// loads), ph1 issues B1' (2). Waits: ph0-end vmcnt(4), ph1-end vmcnt(2) —
// never 0 in steady state. Grid: QKV (24,32)=768=3x256 rounds; out-proj
// (8,32)=256=1 round — both exactly balanced.
// mode 0: scatter q[b,h,l,e], k[b,h,l,e], vT[b,h,e,l]. mode 1: o fp32 +bias.
__global__ __launch_bounds__(512, 2)
void gemm_nt_2ph(const __hip_bfloat16* __restrict__ A,
                 const __hip_bfloat16* __restrict__ W,
                 const float* __restrict__ bias,
                 __hip_bfloat16* __restrict__ q,
                 __hip_bfloat16* __restrict__ k,
                 __hip_bfloat16* __restrict__ vT,
                 float* __restrict__ o,
                 const int mode)
{
    __shared__ char lds[98304];   // [buf 49152][A 16K | B0 16K | B1 16K]

    const int t    = threadIdx.x;
    const int lane = t & 63;
    const int w    = t >> 6;      // 0..7
    const int l15  = lane & 15;
    const int hi   = lane >> 4;
    const int wr   = w >> 2;      // 0..1: 64-row slice of the 128 rows
    const int wc   = w & 3;       // 0..3: 32-col slice within each 128-col half
    const int n0   = blockIdx.x << 8;
    const int m0   = blockIdx.y << 7;

    f32x4 acc[2][4][2];           // [n-half][m][n]
    const f32x4 z4 = {0.f, 0.f, 0.f, 0.f};
    #pragma unroll
    for (int hf = 0; hf < 2; ++hf)
        #pragma unroll
        for (int m = 0; m < 4; ++m)
            #pragma unroll
            for (int n = 0; n < 2; ++n) acc[hf][m][n] = z4;

    s16x8 afr[4][2], bfr[2][2];

    const __hip_bfloat16* Abase = A + (size_t)m0 * K_;
    const __hip_bfloat16* Wbase = W + (size_t)n0 * K_;

    // stage one 128x64 half-tile (2 loads/thread): linear LDS dest,
    // inverse-swizzled global source (involution: 0 conflicts, R6/R7)
    auto stage_half = [&](const __hip_bfloat16* src, char* dst) {
        #pragma unroll
        for (int i = 0; i < 2; ++i) {
            const int slot = (i << 9) + t;          // 0..1023
            const int row  = slot >> 3;             // 0..127
            const int csw  = (slot & 7) ^ (row & 7);
            gld_lds16(src + (size_t)row * K_ + (csw << 3),
                      dst + (i << 13) + (w << 10));
        }
    };

    // prologue: tile 0 -> buf 0 (A, B0, B1 = 6 loads)
    stage_half(Abase,                     lds);
    stage_half(Wbase,                     lds + 16384);
    stage_half(Wbase + (size_t)128 * K_,  lds + 32768);
    asm volatile("s_waitcnt vmcnt(2)" ::: "memory");   // A, B0 done
    __builtin_amdgcn_s_barrier();

    const int NT = K_ / 64;   // 32
    for (int T = 0; T < NT; ++T) {
        const char* Lc = lds + (T & 1) * 49152;
        char*       Ln = lds + ((T & 1) ^ 1) * 49152;
        const __hip_bfloat16* Asrc = Abase + (size_t)(T + 1) * 64;
        const __hip_bfloat16* Wsrc = Wbase + (size_t)(T + 1) * 64;
        const bool pf = (T + 1 < NT);

        auto lda = [&](int m, int kk) {
            const int r  = (wr << 6) + (m << 4) + l15;          // 0..127
            const int ch = ((kk << 2) + hi) ^ (r & 7);
            return *(const s16x8*)(Lc + r * 128 + (ch << 4));
        };
        auto ldb = [&](int reg, int n, int kk) {                // reg: 16384|32768
            const int r  = (wc << 5) + (n << 4) + l15;          // 0..127
            const int ch = ((kk << 2) + hi) ^ (r & 7);
            return *(const s16x8*)(Lc + reg + r * 128 + (ch << 4));
        };

        // ---------- phase 0: C(:, half0) — read A + B0 [12 ds_read_b128]
        #pragma unroll
        for (int m = 0; m < 4; ++m) { afr[m][0] = lda(m, 0); afr[m][1] = lda(m, 1); }
        #pragma unroll
        for (int n = 0; n < 2; ++n) { bfr[n][0] = ldb(16384, n, 0); bfr[n][1] = ldb(16384, n, 1); }
        if (pf) { stage_half(Asrc, Ln); stage_half(Wsrc, Ln + 16384); }
        __builtin_amdgcn_s_barrier();
        __builtin_amdgcn_s_setprio(1);
        #pragma unroll
        for (int kk = 0; kk < 2; ++kk)
            #pragma unroll
            for (int n = 0; n < 2; ++n)
                #pragma unroll
                for (int m = 0; m < 4; ++m)
                    acc[0][m][n] = __builtin_amdgcn_mfma_f32_16x16x32_bf16(
                        afr[m][kk], bfr[n][kk], acc[0][m][n], 0, 0, 0);
        __builtin_amdgcn_s_setprio(0);
        if (pf) asm volatile("s_waitcnt vmcnt(4)" ::: "memory");  // B1(T) done
        else    asm volatile("s_waitcnt vmcnt(0)" ::: "memory");
        __builtin_amdgcn_s_barrier();

        // ---------- phase 1: C(:, half1) — read B1 [4 ds_read_b128]
        #pragma unroll
        for (int n = 0; n < 2; ++n) { bfr[n][0] = ldb(32768, n, 0); bfr[n][1] = ldb(32768, n, 1); }
        if (pf) stage_half(Wsrc + (size_t)128 * K_, Ln + 32768);
        __builtin_amdgcn_s_barrier();
        __builtin_amdgcn_s_setprio(1);
        #pragma unroll
        for (int kk = 0; kk < 2; ++kk)
            #pragma unroll
            for (int n = 0; n < 2; ++n)
                #pragma unroll
                for (int m = 0; m < 4; ++m)
                    acc[1][m][n] = __builtin_amdgcn_mfma_f32_16x16x32_bf16(
                        afr[m][kk], bfr[n][kk], acc[1][m][n], 0, 0, 0);
        __builtin_amdgcn_s_setprio(0);
        asm volatile("s_waitcnt vmcnt(2)" ::: "memory");          // A',B0' done
        __builtin_amdgcn_s_barrier();
    }

    // ---------- epilogue
    #pragma unroll
    for (int hf = 0; hf < 2; ++hf)
        #pragma unroll
        for (int n = 0; n < 2; ++n) {
            const int col  = n0 + (hf << 7) + (wc << 5) + (n << 4) + l15;
            const float bn = bias[col];
            if (mode == 1) {
                #pragma unroll
                for (int m = 0; m < 4; ++m) {
                    const int rowb = m0 + (wr << 6) + (m << 4) + (hi << 2);
                    #pragma unroll
                    for (int i = 0; i < 4; ++i)
                        o[(size_t)(rowb + i) * D_ + col] = acc[hf][m][n][i] + bn;
                }
            } else {
                const int which = col >> 11;
                const int h     = (col >> 7) & 15;
                const int e     = col & 127;
                #pragma unroll
                for (int m = 0; m < 4; ++m) {
                    const int rowb = m0 + (wr << 6) + (m << 4) + (hi << 2);
                    #pragma unroll
                    for (int i = 0; i < 4; ++i) {
                        const int mm = rowb + i;
                        const int b  = mm >> 11;
                        const int l  = mm & 2047;
                        const __hip_bfloat16 val = __float2bfloat16(acc[hf][m][n][i] + bn);
                        if (which == 0)
                            q[((size_t)((b * H_ + h) * L_ + l) << 7) + e] = val;
                        else if (which == 1)
                            k[((size_t)((b * H_ + h) * L_ + l) << 7) + e] = val;
                        else
                            vT[(((size_t)(b * H_ + h) << 7) + e) * L_ + l] = val;
                    }
                }
            }
        }
}

// ---------------- bf16 MFMA causal flash attention ---------------------------
// R5 structure + softmax slim: (a) lane-partial l-sum (no per-tile sum shfls,
// reduced once at end); (b) T13 defer-max (THR=8): skip max-reduce + rescale
// when __all(tmax - m <= 8).
__global__ __launch_bounds__(256)
void attn_mfma(const __hip_bfloat16* __restrict__ Qg,
               const __hip_bfloat16* __restrict__ Kg,
               const __hip_bfloat16* __restrict__ vTg,
               __hip_bfloat16* __restrict__ O)
{
    __shared__ __hip_bfloat16 Ks[2][64 * 128];
    __shared__ __hip_bfloat16 Vt[2][128 * 64];
    __shared__ __hip_bfloat16 Ps[4 * 1024];

    const int t    = threadIdx.x;
    const int lane = t & 63;
    const int w    = t >> 6;
    const int l15  = lane & 15;
    const int hi   = lane >> 4;
    const int pq   = blockIdx.x;
    const int bh   = blockIdx.y;
    const size_t base = (size_t)bh * (L_ * E_);
    const float scale = 0.08838834764831843f;
    const int krow = t >> 4;
    const int kc16 = t & 15;

    const __hip_bfloat16* Kbh  = Kg  + base;
    const __hip_bfloat16* vTbh = vTg + base;

    auto stage = [&](int kt2, int buf) {
        const __hip_bfloat16* Kb = Kbh + ((size_t)(kt2 << 6)) * E_;
        char* kd = (char*)Ks + buf * 16384 + (w << 10);
        #pragma unroll
        for (int j = 0; j < 4; ++j) {
            const int row = (j << 4) + krow;
            const int csw = kc16 ^ (row & 7);
            gld_lds16(Kb + (size_t)row * E_ + (csw << 3), kd + (j << 12));
        }
        const __hip_bfloat16* Vb = vTbh + (kt2 << 6);
        char* vd = (char*)Vt + buf * 16384 + (w << 10);
        #pragma unroll
        for (int j = 0; j < 4; ++j) {
            const int e  = (j << 5) + (t >> 3);
            const int g8 = (t & 7) ^ (e & 7);
            gld_lds16(Vb + (size_t)e * L_ + (g8 << 3), vd + (j << 12));
        }
    };

    const f32x4 z4 = {0.f, 0.f, 0.f, 0.f};

    #pragma unroll 1
    for (int seg = 0; seg < 2; ++seg) {
        const int qt = seg ? pq : 31 - pq;
        const int q0 = (qt << 6) + (w << 4);

        s16x8 qf[4];
        #pragma unroll
        for (int e0 = 0; e0 < 4; ++e0)
            qf[e0] = *(const s16x8*)(Qg + base + (size_t)(q0 + l15) * E_ + e0 * 32 + hi * 8);

        f32x4 oacc[8];
        #pragma unroll
        for (int ef = 0; ef < 8; ++ef) oacc[ef] = z4;
        float mrow[4] = {-1e30f, -1e30f, -1e30f, -1e30f};
        float lsum[4] = {0.f, 0.f, 0.f, 0.f};          // lane-partial

        stage(0, 0);
        __syncthreads();

        for (int kt = 0; kt <= qt; ++kt) {
            const int cur = kt & 1;
            if (kt < qt) stage(kt + 1, cur ^ 1);

            const char* Ksc = (const char*)Ks + cur * 16384;
            const char* Vtc = (const char*)Vt + cur * 16384;

            f32x4 sf[4];
            #pragma unroll
            for (int c = 0; c < 4; ++c) {
                f32x4 s = z4;
                const int row = (c << 4) + l15;
                #pragma unroll
                for (int e0 = 0; e0 < 4; ++e0) {
                    const int ch = ((e0 << 2) + hi) ^ (row & 7);
                    const s16x8 kf = *(const s16x8*)(Ksc + (row << 8) + (ch << 4));
                    s = __builtin_amdgcn_mfma_f32_16x16x32_bf16(qf[e0], kf, s, 0, 0, 0);
                }
                sf[c] = s;
            }

            // ---- scale + mask + per-lane tile max
            float p4[4][4];
            float tmax[4] = {-1e30f, -1e30f, -1e30f, -1e30f};
            if (kt == qt) {
                const int qg = q0 + (hi << 2);
                #pragma unroll
                for (int c = 0; c < 4; ++c) {
                    const int kvg = (kt << 6) + (c << 4) + l15;
                    #pragma unroll
                    for (int i = 0; i < 4; ++i) {
                        float s = sf[c][i] * scale;
                        if (kvg > qg + i) s = -1e30f;
                        p4[c][i] = s;
                        tmax[i] = fmaxf(tmax[i], s);
                    }
                }
            } else {
                #pragma unroll
                for (int c = 0; c < 4; ++c)
                    #pragma unroll
                    for (int i = 0; i < 4; ++i) {
                        const float s = sf[c][i] * scale;
                        p4[c][i] = s;
                        tmax[i] = fmaxf(tmax[i], s);
                    }
            }

            // ---- T13 defer-max: reduce+rescale only when max grew > THR
            int ok = 1;
            #pragma unroll
            for (int i = 0; i < 4; ++i) ok &= (tmax[i] <= mrow[i] + 8.f);
            if (!__all(ok)) {
                #pragma unroll
                for (int i = 0; i < 4; ++i) {
                    float v = tmax[i];
                    v = fmaxf(v, __shfl_xor(v, 1));
                    v = fmaxf(v, __shfl_xor(v, 2));
                    v = fmaxf(v, __shfl_xor(v, 4));
                    v = fmaxf(v, __shfl_xor(v, 8));
                    const float mnew = fmaxf(mrow[i], v);
                    const float fsc  = __expf(mrow[i] - mnew);
                    mrow[i] = mnew;
                    lsum[i] *= fsc;
                    #pragma unroll
                    for (int ef = 0; ef < 8; ++ef) oacc[ef][i] *= fsc;
                }
            }
            // ---- exp + lane-partial sum
            #pragma unroll
            for (int i = 0; i < 4; ++i)
                #pragma unroll
                for (int c = 0; c < 4; ++c) {
                    const float pe = __expf(p4[c][i] - mrow[i]);
                    p4[c][i] = pe;
                    lsum[i] += pe;
                }

            // ---- P -> LDS (bf16, swizzled), then PV
            #pragma unroll
            for (int c = 0; c < 4; ++c)
                #pragma unroll
                for (int i = 0; i < 4; ++i) {
                    const int r   = (hi << 2) + i;
                    const int col = (c << 4) + l15;
                    const int ch  = (col >> 3) ^ (r & 7);
                    const int by  = (r << 7) + ((ch << 4) | ((col & 7) << 1));
                    *(__hip_bfloat16*)((char*)Ps + (w << 11) + by) = __float2bfloat16(p4[c][i]);
                }
            asm volatile("s_waitcnt lgkmcnt(0)" ::: "memory");

            #pragma unroll
            for (int kh = 0; kh < 2; ++kh) {
                const int chp = ((kh << 2) + hi) ^ (l15 & 7);
                const s16x8 pa = *(const s16x8*)((char*)Ps + (w << 11) + (l15 << 7) + (chp << 4));
                #pragma unroll
                for (int ef = 0; ef < 8; ++ef) {
                    const int e   = (ef << 4) + l15;
                    const int chv = ((kh << 2) + hi) ^ (e & 7);
                    const s16x8 vb = *(const s16x8*)(Vtc + (e << 7) + (chv << 4));
                    oacc[ef] = __builtin_amdgcn_mfma_f32_16x16x32_bf16(pa, vb, oacc[ef], 0, 0, 0);
                }
            }
            __syncthreads();
        }

        // ---- final l reduce (once per seg) + epilogue
        float invl[4];
        #pragma unroll
        for (int i = 0; i < 4; ++i) {
            float s = lsum[i];
            s += __shfl_xor(s, 1);
            s += __shfl_xor(s, 2);
            s += __shfl_xor(s, 4);
            s += __shfl_xor(s, 8);
            invl[i] = 1.f / s;
        }
        const int b = bh >> 4, h = bh & 15;
        #pragma unroll
        for (int ef = 0; ef < 8; ++ef) {
            const int e = (ef << 4) + l15;
            #pragma unroll
            for (int i = 0; i < 4; ++i) {
                const int row = q0 + (hi << 2) + i;
                O[((size_t)(b * L_ + row) * D_) + (h << 7) + e] =
                    __float2bfloat16(oacc[ef][i] * invl[i]);
            }
        }
    }
}

extern "C" void kernel_launch(void* const* d_in, const int* in_sizes, int n_in,
                              void* d_out, int out_size, void* d_ws, size_t ws_size,
                              hipStream_t stream)
{
    const float* x    = (const float*)d_in[0];
    const float* Wqkv = (const float*)d_in[1];
    const float* bqkv = (const float*)d_in[2];
    const float* Wout = (const float*)d_in[3];
    const float* bout = (const float*)d_in[4];
    float* out = (float*)d_out;

    __hip_bfloat16* xb  = (__hip_bfloat16*)d_ws;
    __hip_bfloat16* wqb = xb  + (size_t)M_ * K_;
    __hip_bfloat16* wob = wqb + (size_t)N3_ * K_;
    __hip_bfloat16* qb  = wob + (size_t)D_ * K_;
    __hip_bfloat16* kb  = qb  + (size_t)M_ * D_;
    __hip_bfloat16* vtb = kb  + (size_t)M_ * D_;   // vT[b,h,e,l]
    __hip_bfloat16* aob = vtb + (size_t)M_ * D_;

    const int na = M_ * K_ / 8, nb = N3_ * K_ / 8, nc = D_ * K_ / 8;
    cast3_bf16<<<(na + nb + nc) / 256, 256, 0, stream>>>(x, xb, na, Wqkv, wqb, nb, Wout, wob, nc);

    dim3 g1(N3_ / 256, M_ / 128);   // 24 x 32 = 768 = 3 x 256 (balanced)
    gemm_nt_2ph<<<g1, dim3(512), 0, stream>>>(xb, wqb, bqkv, qb, kb, vtb, nullptr, 0);

    dim3 g2(16, B_ * H_);           // paired q-tiles
    attn_mfma<<<g2, dim3(256), 0, stream>>>(qb, kb, vtb, aob);

    dim3 g3(D_ / 256, M_ / 128);    // 8 x 32 = 256 = 1 round (balanced)
    gemm_nt_2ph<<<g3, dim3(512), 0, stream>>>(aob, wob, bout, nullptr, nullptr, nullptr, out, 1);
}